// Round 6
// baseline (260.401 us; speedup 1.0000x reference)
//
#include <hip/hip_runtime.h>
#include <hip/hip_bf16.h>
#include <math.h>

#define HDIM 1024
#define NHEADS 16
#define HEADD 64
#define SEQLEN 2048
#define NBATCH 2
#define NROWS (NBATCH*SEQLEN)
#define NBH (NBATCH*NHEADS)
#define LOG2E 1.44269504f

typedef float f32x4 __attribute__((ext_vector_type(4)));
typedef float f32x16 __attribute__((ext_vector_type(16)));
typedef short short8 __attribute__((ext_vector_type(8)));
typedef unsigned short us4v __attribute__((ext_vector_type(4)));

#define GLOBAL_AS __attribute__((address_space(1)))
#define LDS_AS __attribute__((address_space(3)))

union F4 { float4 v; float f[4]; };
union PW { unsigned int u[4]; short8 s; };

static __device__ __forceinline__ unsigned short f2bf(float x) {
    __hip_bfloat16 h = __float2bfloat16(x);
    return *(unsigned short*)&h;
}

// ---------------- LayerNorm -> bf16 ----------------
__global__ __launch_bounds__(256) void ln_kernel(
        const float* __restrict__ x, const float* __restrict__ w,
        const float* __restrict__ b, unsigned short* __restrict__ xn) {
    int row = blockIdx.x;
    F4 vv; vv.v = ((const float4*)(x + (size_t)row*HDIM))[threadIdx.x];
    float s  = vv.f[0]+vv.f[1]+vv.f[2]+vv.f[3];
    float ss = vv.f[0]*vv.f[0]+vv.f[1]*vv.f[1]+vv.f[2]*vv.f[2]+vv.f[3]*vv.f[3];
    #pragma unroll
    for (int off = 32; off > 0; off >>= 1) {
        s  += __shfl_xor(s, off);
        ss += __shfl_xor(ss, off);
    }
    __shared__ float red[8];
    int wid = threadIdx.x >> 6;
    if ((threadIdx.x & 63) == 0) { red[wid] = s; red[wid+4] = ss; }
    __syncthreads();
    s  = red[0]+red[1]+red[2]+red[3];
    ss = red[4]+red[5]+red[6]+red[7];
    float mean = s * (1.0f/HDIM);
    float var  = ss * (1.0f/HDIM) - mean*mean;
    float rstd = rsqrtf(var + 1e-5f);
    F4 wv; wv.v = ((const float4*)w)[threadIdx.x];
    F4 bv; bv.v = ((const float4*)b)[threadIdx.x];
    us4v o;
    #pragma unroll
    for (int j = 0; j < 4; ++j)
        o[j] = f2bf((vv.f[j]-mean)*rstd*wv.f[j] + bv.f[j]);
    *(us4v*)(xn + (size_t)row*HDIM + threadIdx.x*4) = o;
}

// ---------- weight convert+transpose: W[k][n] f32 -> Wt[n][k] bf16 ----------
__global__ __launch_bounds__(256) void wconv_kernel(
        const float* __restrict__ W, unsigned short* __restrict__ Wt) {
    __shared__ unsigned short T[64*72];
    int k0 = blockIdx.x*64, n0 = blockIdx.y*64;
    int t = threadIdx.x;
    #pragma unroll
    for (int it = 0; it < 4; ++it) {
        int r = (t>>4) + it*16;
        int c = (t&15)*4;
        F4 x; x.v = *(const float4*)(W + (size_t)(k0+r)*HDIM + n0 + c);
        #pragma unroll
        for (int j = 0; j < 4; ++j) T[(c+j)*72 + r] = f2bf(x.f[j]);
    }
    __syncthreads();
    #pragma unroll
    for (int it = 0; it < 2; ++it) {
        int n = (t>>3) + it*32;
        int ch = t&7;
        short8 rowv = *(const short8*)(T + n*72 + ch*8);
        *(short8*)(Wt + (size_t)(n0+n)*HDIM + k0 + ch*8) = rowv;
    }
}

// ---------------- bf16 MFMA GEMM: C = A @ Wt^T (+bias), 2-phase dbuf ----------------
template<int MODE>
__global__ __launch_bounds__(256) void gemm_mfma_kernel(
        const unsigned short* __restrict__ A,
        const unsigned short* __restrict__ Wt,
        const float* __restrict__ bias,
        const float* __restrict__ residual,
        void* __restrict__ outp, float oscale) {
    __shared__ unsigned short As[2][128*64];
    __shared__ unsigned short Bs[2][128*64];
    int m0 = blockIdx.x * 128;
    int n0 = blockIdx.y * 128;
    int t = threadIdx.x;
    int wid = t >> 6, l = t & 63;
    int wm = wid >> 1, wn = wid & 1;
    int lq = l & 15, g = l >> 4;
    f32x4 acc[4][4];
    #pragma unroll
    for (int mi = 0; mi < 4; ++mi)
        #pragma unroll
        for (int ni = 0; ni < 4; ++ni) acc[mi][ni] = 0.0f;

    auto STAGE = [&](int b, int k0) {
        #pragma unroll
        for (int i = 0; i < 4; ++i) {
            int idx = t + 256*i;
            int r = idx >> 3, ch = idx & 7;
            int gch = ch ^ (r & 7);
            __builtin_amdgcn_global_load_lds(
                (const GLOBAL_AS void*)(A + (size_t)(m0+r)*HDIM + k0 + gch*8),
                (LDS_AS void*)((char*)&As[b][0] + idx*16), 16, 0, 0);
            __builtin_amdgcn_global_load_lds(
                (const GLOBAL_AS void*)(Wt + (size_t)(n0+r)*HDIM + k0 + gch*8),
                (LDS_AS void*)((char*)&Bs[b][0] + idx*16), 16, 0, 0);
        }
    };

    STAGE(0, 0);
    asm volatile("s_waitcnt vmcnt(0)" ::: "memory");
    __builtin_amdgcn_s_barrier();
    asm volatile("" ::: "memory");
    int buf = 0;
    for (int ks = 0; ks < 16; ++ks) {
        if (ks < 15) STAGE(buf^1, (ks+1)*64);
        const char* Ab = (const char*)&As[buf][0];
        const char* Bb = (const char*)&Bs[buf][0];
        #pragma unroll
        for (int kc = 0; kc < 2; ++kc) {
            short8 af[4], bf[4];
            #pragma unroll
            for (int mi = 0; mi < 4; ++mi) {
                int r = wm*64 + mi*16 + lq;
                af[mi] = *(const short8*)(Ab + r*128 + (((kc*4+g) ^ (r&7))<<4));
            }
            #pragma unroll
            for (int ni = 0; ni < 4; ++ni) {
                int r = wn*64 + ni*16 + lq;
                bf[ni] = *(const short8*)(Bb + r*128 + (((kc*4+g) ^ (r&7))<<4));
            }
            #pragma unroll
            for (int mi = 0; mi < 4; ++mi)
                #pragma unroll
                for (int ni = 0; ni < 4; ++ni)
                    acc[mi][ni] = __builtin_amdgcn_mfma_f32_16x16x32_bf16(
                        af[mi], bf[ni], acc[mi][ni], 0, 0, 0);
        }
        asm volatile("s_waitcnt vmcnt(0)" ::: "memory");
        __builtin_amdgcn_s_barrier();
        asm volatile("" ::: "memory");
        buf ^= 1;
    }
    // -------- epilogue --------
    float bv[4];
    #pragma unroll
    for (int ni = 0; ni < 4; ++ni) bv[ni] = bias[n0 + wn*64 + ni*16 + lq];
    #pragma unroll
    for (int mi = 0; mi < 4; ++mi)
        #pragma unroll
        for (int ni = 0; ni < 4; ++ni)
            #pragma unroll
            for (int i = 0; i < 4; ++i) acc[mi][ni][i] += bv[ni];
    if (MODE == 0) {
        int h = (n0 >> 6) + wn;
        #pragma unroll
        for (int mi = 0; mi < 4; ++mi) {
            f32x4 ss = 0.0f;
            #pragma unroll
            for (int ni = 0; ni < 4; ++ni)
                #pragma unroll
                for (int i = 0; i < 4; ++i) ss[i] += acc[mi][ni][i]*acc[mi][ni][i];
            #pragma unroll
            for (int off = 1; off < 16; off <<= 1)
                #pragma unroll
                for (int i = 0; i < 4; ++i) ss[i] += __shfl_xor(ss[i], off);
            #pragma unroll
            for (int i = 0; i < 4; ++i) {
                float sc = oscale / fmaxf(sqrtf(ss[i]), 1e-12f);
                int m = m0 + wm*64 + mi*16 + g*4 + i;
                int bb = m >> 11, sq = m & (SEQLEN-1);
                unsigned short* orow = (unsigned short*)outp
                    + ((size_t)(bb*NHEADS + h)*SEQLEN + sq)*HEADD;
                #pragma unroll
                for (int ni = 0; ni < 4; ++ni)
                    orow[ni*16 + lq] = f2bf(acc[mi][ni][i] * sc);
            }
        }
    } else if (MODE == 1) {
        int h = (n0 >> 6) + wn;
        #pragma unroll
        for (int mi = 0; mi < 4; ++mi) {
            int m = m0 + wm*64 + mi*16 + g*4;
            int bb = m >> 11, sq = m & (SEQLEN-1);
            #pragma unroll
            for (int ni = 0; ni < 4; ++ni) {
                int d = ni*16 + lq;
                us4v pk;
                #pragma unroll
                for (int i = 0; i < 4; ++i) pk[i] = f2bf(acc[mi][ni][i]);
                *(us4v*)((unsigned short*)outp
                    + ((size_t)(bb*NHEADS + h)*HEADD + d)*SEQLEN + sq) = pk;
            }
        }
    } else {
        #pragma unroll
        for (int mi = 0; mi < 4; ++mi)
            #pragma unroll
            for (int i = 0; i < 4; ++i) {
                int m = m0 + wm*64 + mi*16 + g*4 + i;
                float* orow = (float*)outp + (size_t)m*HDIM;
                const float* rrow = residual + (size_t)m*HDIM;
                #pragma unroll
                for (int ni = 0; ni < 4; ++ni) {
                    int n = n0 + wn*64 + ni*16 + lq;
                    orow[n] = acc[mi][ni][i] + rrow[n];
                }
            }
    }
}

// ---------------- 32x32-MFMA flash attention, 2 q-tiles/wave ----------------
// K/V-frag A-operands reused across both q-sets -> LDS reads per MFMA halved.
// 3-buffer counted-vmcnt pipeline (never drain to 0 mid-loop).
// qg: state bf16 [bh][S][64] PRE-SCALED by log2e; kg unit rows; vtg V^T [bh][64][S]
template<int OUTMODE>
__global__ __launch_bounds__(128, 1) void attn3_kernel(
        const unsigned short* __restrict__ qg, const unsigned short* __restrict__ kg,
        const unsigned short* __restrict__ vtg, unsigned short* __restrict__ outp) {
    __shared__ unsigned short L[3][2*4096];   // 48 KiB: 3 × (K 8KB | V 8KB)
    // XCD-bijective swizzle: all 16 q-blocks of a head on one XCD (4 heads/XCD -> 2MB L2)
    int b = blockIdx.x;
    int bh = (b & 7)*4 + ((b >> 3) & 3);
    int q0 = (b >> 5) * 128;
    int t = threadIdx.x;              // 0..127, 2 waves
    int wq = t >> 6, l = t & 63;
    int q = l & 31, hi = l >> 5, r7 = q & 7;
    // Q fragments for 2 q-sets: rows q0+wq*64+q (A) and +32 (B)
    short8 qfA[4], qfB[4];
    {
        const unsigned short* qrowA = qg + ((size_t)bh*SEQLEN + q0 + wq*64 + q)*HEADD;
        const unsigned short* qrowB = qrowA + 32*HEADD;
        #pragma unroll
        for (int dc = 0; dc < 4; ++dc) {
            qfA[dc] = *(const short8*)(qrowA + dc*16 + hi*8);
            qfB[dc] = *(const short8*)(qrowB + dc*16 + hi*8);
        }
    }
    int koffv[4];
    #pragma unroll
    for (int x = 0; x < 4; ++x) koffv[x] = q*128 + (((x*2 + hi) ^ r7) << 4);

    f32x16 oA0 = 0.0f, oA1 = 0.0f, oB0 = 0.0f, oB1 = 0.0f;
    float lsA = 0.0f, lsB = 0.0f;
    const unsigned short* Kg = kg + (size_t)bh*SEQLEN*HEADD;
    const unsigned short* Vg = vtg + (size_t)bh*HEADD*SEQLEN;

    // staging: lane-linear 16B chunks, pre-swizzled global source (rule 21)
    auto STAGE = [&](int bf, int kt) {
        #pragma unroll
        for (int i = 0; i < 4; ++i) {
            int idx = t + 128*i;              // chunk 0..511
            int r = idx >> 3, ch = idx & 7;
            int gch = ch ^ (r & 7);
            __builtin_amdgcn_global_load_lds(
                (const GLOBAL_AS void*)(Kg + (size_t)(kt*64 + r)*HEADD + gch*8),
                (LDS_AS void*)((char*)&L[bf][0] + idx*16), 16, 0, 0);
            __builtin_amdgcn_global_load_lds(
                (const GLOBAL_AS void*)(Vg + (size_t)r*SEQLEN + kt*64 + gch*8),
                (LDS_AS void*)((char*)&L[bf][0] + 8192 + idx*16), 16, 0, 0);
        }
    };  // 8 loads per thread per tile

    const int NT = SEQLEN/64;
    STAGE(0, 0);
    STAGE(1, 1);
    asm volatile("s_waitcnt vmcnt(8)" ::: "memory");   // tile0 done, tile1 in flight
    __builtin_amdgcn_s_barrier();
    asm volatile("" ::: "memory");
    int cur = 0;
    for (int kt = 0; kt < NT; ++kt) {
        if (kt + 2 < NT) {
            int pre = cur + 2; if (pre >= 3) pre -= 3;
            STAGE(pre, kt + 2);
        }
        const char* KL = (const char*)&L[0][0] + cur*16384;
        const char* VL = KL + 8192;
        #pragma unroll
        for (int h = 0; h < 2; ++h) {     // key halves: keys h*32..h*32+31
            short8 kf[4];
            #pragma unroll
            for (int dc = 0; dc < 4; ++dc)
                kf[dc] = *(const short8*)(KL + koffv[dc] + h*4096);
            f32x16 sA = 0.0f, sB = 0.0f;
            __builtin_amdgcn_s_setprio(1);
            #pragma unroll
            for (int dc = 0; dc < 4; ++dc) {
                sA = __builtin_amdgcn_mfma_f32_32x32x16_bf16(kf[dc], qfA[dc], sA, 0, 0, 0);
                sB = __builtin_amdgcn_mfma_f32_32x32x16_bf16(kf[dc], qfB[dc], sB, 0, 0, 0);
            }
            __builtin_amdgcn_s_setprio(0);
            unsigned int wA[8], wB[8];
            #pragma unroll
            for (int i = 0; i < 8; ++i) {
                float a0 = exp2f(sA[2*i]), a1 = exp2f(sA[2*i+1]);
                lsA += a0 + a1;
                asm("v_cvt_pk_bf16_f32 %0, %1, %2" : "=v"(wA[i]) : "v"(a0), "v"(a1));
                float b0 = exp2f(sB[2*i]), b1 = exp2f(sB[2*i+1]);
                lsB += b0 + b1;
                asm("v_cvt_pk_bf16_f32 %0, %1, %2" : "=v"(wB[i]) : "v"(b0), "v"(b1));
            }
            asm volatile("v_permlane32_swap_b32 %0, %1" : "+v"(wA[0]), "+v"(wA[2]));
            asm volatile("v_permlane32_swap_b32 %0, %1" : "+v"(wA[1]), "+v"(wA[3]));
            asm volatile("v_permlane32_swap_b32 %0, %1" : "+v"(wA[4]), "+v"(wA[6]));
            asm volatile("v_permlane32_swap_b32 %0, %1" : "+v"(wA[5]), "+v"(wA[7]));
            asm volatile("v_permlane32_swap_b32 %0, %1" : "+v"(wB[0]), "+v"(wB[2]));
            asm volatile("v_permlane32_swap_b32 %0, %1" : "+v"(wB[1]), "+v"(wB[3]));
            asm volatile("v_permlane32_swap_b32 %0, %1" : "+v"(wB[4]), "+v"(wB[6]));
            asm volatile("v_permlane32_swap_b32 %0, %1" : "+v"(wB[5]), "+v"(wB[7]));
            #pragma unroll
            for (int c = 0; c < 2; ++c) {
                int j = h*2 + c;              // key k-slice index
                short8 vf0 = *(const short8*)(VL + koffv[j]);
                short8 vf1 = *(const short8*)(VL + koffv[j] + 4096);
                PW pA, pB;
                pA.u[0] = wA[c*4+0]; pA.u[1] = wA[c*4+1];
                pA.u[2] = wA[c*4+2]; pA.u[3] = wA[c*4+3];
                pB.u[0] = wB[c*4+0]; pB.u[1] = wB[c*4+1];
                pB.u[2] = wB[c*4+2]; pB.u[3] = wB[c*4+3];
                __builtin_amdgcn_s_setprio(1);
                oA0 = __builtin_amdgcn_mfma_f32_32x32x16_bf16(vf0, pA.s, oA0, 0, 0, 0);
                oA1 = __builtin_amdgcn_mfma_f32_32x32x16_bf16(vf1, pA.s, oA1, 0, 0, 0);
                oB0 = __builtin_amdgcn_mfma_f32_32x32x16_bf16(vf0, pB.s, oB0, 0, 0, 0);
                oB1 = __builtin_amdgcn_mfma_f32_32x32x16_bf16(vf1, pB.s, oB1, 0, 0, 0);
                __builtin_amdgcn_s_setprio(0);
            }
        }
        // counted drain: tile kt+1's 8 loads must land; kt+2's 8 stay in flight
        if (kt + 2 < NT) asm volatile("s_waitcnt vmcnt(8)" ::: "memory");
        else             asm volatile("s_waitcnt vmcnt(0)" ::: "memory");
        __builtin_amdgcn_s_barrier();
        asm volatile("" ::: "memory");
        cur = (cur == 2) ? 0 : cur + 1;
    }
    // ---- epilogue ----
    lsA += __shfl_xor(lsA, 32);
    lsB += __shfl_xor(lsB, 32);
    float oscA = 1.0f / lsA, oscB = 1.0f / lsB;
    if (OUTMODE == 0) { oscA *= LOG2E; oscB *= LOG2E; }
    int rowA = q0 + wq*64 + q, rowB = rowA + 32;
    unsigned short *orowA, *orowB;
    if (OUTMODE == 0) {
        orowA = outp + ((size_t)bh*SEQLEN + rowA)*HEADD;
        orowB = outp + ((size_t)bh*SEQLEN + rowB)*HEADD;
    } else {
        int bb = bh >> 4, hh = bh & 15;
        orowA = outp + ((size_t)bb*SEQLEN + rowA)*HDIM + hh*HEADD;
        orowB = outp + ((size_t)bb*SEQLEN + rowB)*HDIM + hh*HEADD;
    }
    const int dtab[8] = {0,2,8,10,16,18,24,26};
    #pragma unroll
    for (int i = 0; i < 8; ++i) {
        int d = dtab[i] + 4*hi;
        unsigned int wv;
        float a0 = oA0[2*i]*oscA, a1 = oA0[2*i+1]*oscA;
        asm("v_cvt_pk_bf16_f32 %0, %1, %2" : "=v"(wv) : "v"(a0), "v"(a1));
        *(unsigned int*)(orowA + d) = wv;
        float c0 = oB0[2*i]*oscB, c1 = oB0[2*i+1]*oscB;
        asm("v_cvt_pk_bf16_f32 %0, %1, %2" : "=v"(wv) : "v"(c0), "v"(c1));
        *(unsigned int*)(orowB + d) = wv;
    }
    #pragma unroll
    for (int i = 0; i < 8; ++i) {
        int d = 32 + dtab[i] + 4*hi;
        unsigned int wv;
        float a0 = oA1[2*i]*oscA, a1 = oA1[2*i+1]*oscA;
        asm("v_cvt_pk_bf16_f32 %0, %1, %2" : "=v"(wv) : "v"(a0), "v"(a1));
        *(unsigned int*)(orowA + d) = wv;
        float c0 = oB1[2*i]*oscB, c1 = oB1[2*i+1]*oscB;
        asm("v_cvt_pk_bf16_f32 %0, %1, %2" : "=v"(wv) : "v"(c0), "v"(c1));
        *(unsigned int*)(orowB + d) = wv;
    }
}

extern "C" void kernel_launch(void* const* d_in, const int* in_sizes, int n_in,
                              void* d_out, int out_size, void* d_ws, size_t ws_size,
                              hipStream_t stream) {
    const float* hs = (const float*)d_in[0];
    const float* Wq = (const float*)d_in[1];
    const float* bq = (const float*)d_in[2];
    const float* Wk = (const float*)d_in[3];
    const float* bk = (const float*)d_in[4];
    const float* Wv = (const float*)d_in[5];
    const float* bv = (const float*)d_in[6];
    const float* Wo = (const float*)d_in[7];
    const float* bo = (const float*)d_in[8];
    const float* lw = (const float*)d_in[9];
    const float* lb = (const float*)d_in[10];
    unsigned short* ws16 = (unsigned short*)d_ws;
    const size_t NE = (size_t)NROWS * HDIM;
    const size_t WE = (size_t)HDIM * HDIM;
    unsigned short* xn  = ws16;
    unsigned short* Wtq = xn + NE;
    unsigned short* Wtk = Wtq + WE;
    unsigned short* Wtv = Wtk + WE;
    unsigned short* Wto = Wtv + WE;
    unsigned short* qb  = Wto + WE;
    unsigned short* kb  = qb + NE;
    unsigned short* vt  = kb + NE;
    unsigned short* s1  = vt + NE;
    unsigned short* s2  = s1 + NE;

    ln_kernel<<<NROWS, 256, 0, stream>>>(hs, lw, lb, xn);
    dim3 wg(HDIM/64, HDIM/64);
    wconv_kernel<<<wg, 256, 0, stream>>>(Wq, Wtq);
    wconv_kernel<<<wg, 256, 0, stream>>>(Wk, Wtk);
    wconv_kernel<<<wg, 256, 0, stream>>>(Wv, Wtv);
    wconv_kernel<<<wg, 256, 0, stream>>>(Wo, Wto);
    dim3 gg(NROWS/128, HDIM/128);
    // q pre-scaled by log2e (exp2-domain softmax); k unit-normalized
    gemm_mfma_kernel<0><<<gg, 256, 0, stream>>>(xn, Wtq, bq, nullptr, qb, LOG2E);
    gemm_mfma_kernel<0><<<gg, 256, 0, stream>>>(xn, Wtk, bk, nullptr, kb, 1.0f);
    gemm_mfma_kernel<1><<<gg, 256, 0, stream>>>(xn, Wtv, bv, nullptr, vt, 1.0f);
    attn3_kernel<0><<<NBH*16, 128, 0, stream>>>(qb, kb, vt, s1);
    attn3_kernel<1><<<NBH*16, 128, 0, stream>>>(s1, kb, vt, s2);
    gemm_mfma_kernel<2><<<gg, 256, 0, stream>>>(s2, Wto, bo, hs, (void*)d_out, 1.0f);
}

// Round 7
// 219.880 us; speedup vs baseline: 1.1843x; 1.1843x over previous
//
#include <hip/hip_runtime.h>
#include <hip/hip_bf16.h>
#include <math.h>

#define HDIM 1024
#define NHEADS 16
#define HEADD 64
#define SEQLEN 2048
#define NBATCH 2
#define NROWS (NBATCH*SEQLEN)
#define NBH (NBATCH*NHEADS)
#define LOG2E 1.44269504f

typedef float f32x4 __attribute__((ext_vector_type(4)));
typedef float f32x16 __attribute__((ext_vector_type(16)));
typedef short short8 __attribute__((ext_vector_type(8)));
typedef unsigned short us4v __attribute__((ext_vector_type(4)));

#define GLOBAL_AS __attribute__((address_space(1)))
#define LDS_AS __attribute__((address_space(3)))

union F4 { float4 v; float f[4]; };
union PW { unsigned int u[4]; short8 s; };

static __device__ __forceinline__ unsigned short f2bf(float x) {
    __hip_bfloat16 h = __float2bfloat16(x);
    return *(unsigned short*)&h;
}

// ---------------- LayerNorm -> bf16 ----------------
__global__ __launch_bounds__(256) void ln_kernel(
        const float* __restrict__ x, const float* __restrict__ w,
        const float* __restrict__ b, unsigned short* __restrict__ xn) {
    int row = blockIdx.x;
    F4 vv; vv.v = ((const float4*)(x + (size_t)row*HDIM))[threadIdx.x];
    float s  = vv.f[0]+vv.f[1]+vv.f[2]+vv.f[3];
    float ss = vv.f[0]*vv.f[0]+vv.f[1]*vv.f[1]+vv.f[2]*vv.f[2]+vv.f[3]*vv.f[3];
    #pragma unroll
    for (int off = 32; off > 0; off >>= 1) {
        s  += __shfl_xor(s, off);
        ss += __shfl_xor(ss, off);
    }
    __shared__ float red[8];
    int wid = threadIdx.x >> 6;
    if ((threadIdx.x & 63) == 0) { red[wid] = s; red[wid+4] = ss; }
    __syncthreads();
    s  = red[0]+red[1]+red[2]+red[3];
    ss = red[4]+red[5]+red[6]+red[7];
    float mean = s * (1.0f/HDIM);
    float var  = ss * (1.0f/HDIM) - mean*mean;
    float rstd = rsqrtf(var + 1e-5f);
    F4 wv; wv.v = ((const float4*)w)[threadIdx.x];
    F4 bv; bv.v = ((const float4*)b)[threadIdx.x];
    us4v o;
    #pragma unroll
    for (int j = 0; j < 4; ++j)
        o[j] = f2bf((vv.f[j]-mean)*rstd*wv.f[j] + bv.f[j]);
    *(us4v*)(xn + (size_t)row*HDIM + threadIdx.x*4) = o;
}

// ---------- weight convert+transpose: W[k][n] f32 -> Wt[n][k] bf16 ----------
__global__ __launch_bounds__(256) void wconv_kernel(
        const float* __restrict__ W, unsigned short* __restrict__ Wt) {
    __shared__ unsigned short T[64*72];
    int k0 = blockIdx.x*64, n0 = blockIdx.y*64;
    int t = threadIdx.x;
    #pragma unroll
    for (int it = 0; it < 4; ++it) {
        int r = (t>>4) + it*16;
        int c = (t&15)*4;
        F4 x; x.v = *(const float4*)(W + (size_t)(k0+r)*HDIM + n0 + c);
        #pragma unroll
        for (int j = 0; j < 4; ++j) T[(c+j)*72 + r] = f2bf(x.f[j]);
    }
    __syncthreads();
    #pragma unroll
    for (int it = 0; it < 2; ++it) {
        int n = (t>>3) + it*32;
        int ch = t&7;
        short8 rowv = *(const short8*)(T + n*72 + ch*8);
        *(short8*)(Wt + (size_t)(n0+n)*HDIM + k0 + ch*8) = rowv;
    }
}

// ---------------- bf16 MFMA GEMM: C = A @ Wt^T (+bias), 2-phase dbuf ----------------
template<int MODE>
__global__ __launch_bounds__(256) void gemm_mfma_kernel(
        const unsigned short* __restrict__ A,
        const unsigned short* __restrict__ Wt,
        const float* __restrict__ bias,
        const float* __restrict__ residual,
        void* __restrict__ outp, float oscale) {
    __shared__ unsigned short As[2][128*64];
    __shared__ unsigned short Bs[2][128*64];
    int m0 = blockIdx.x * 128;
    int n0 = blockIdx.y * 128;
    int t = threadIdx.x;
    int wid = t >> 6, l = t & 63;
    int wm = wid >> 1, wn = wid & 1;
    int lq = l & 15, g = l >> 4;
    f32x4 acc[4][4];
    #pragma unroll
    for (int mi = 0; mi < 4; ++mi)
        #pragma unroll
        for (int ni = 0; ni < 4; ++ni) acc[mi][ni] = 0.0f;

    auto STAGE = [&](int b, int k0) {
        #pragma unroll
        for (int i = 0; i < 4; ++i) {
            int idx = t + 256*i;
            int r = idx >> 3, ch = idx & 7;
            int gch = ch ^ (r & 7);
            __builtin_amdgcn_global_load_lds(
                (const GLOBAL_AS void*)(A + (size_t)(m0+r)*HDIM + k0 + gch*8),
                (LDS_AS void*)((char*)&As[b][0] + idx*16), 16, 0, 0);
            __builtin_amdgcn_global_load_lds(
                (const GLOBAL_AS void*)(Wt + (size_t)(n0+r)*HDIM + k0 + gch*8),
                (LDS_AS void*)((char*)&Bs[b][0] + idx*16), 16, 0, 0);
        }
    };

    STAGE(0, 0);
    asm volatile("s_waitcnt vmcnt(0)" ::: "memory");
    __builtin_amdgcn_s_barrier();
    asm volatile("" ::: "memory");
    int buf = 0;
    for (int ks = 0; ks < 16; ++ks) {
        if (ks < 15) STAGE(buf^1, (ks+1)*64);
        const char* Ab = (const char*)&As[buf][0];
        const char* Bb = (const char*)&Bs[buf][0];
        #pragma unroll
        for (int kc = 0; kc < 2; ++kc) {
            short8 af[4], bf[4];
            #pragma unroll
            for (int mi = 0; mi < 4; ++mi) {
                int r = wm*64 + mi*16 + lq;
                af[mi] = *(const short8*)(Ab + r*128 + (((kc*4+g) ^ (r&7))<<4));
            }
            #pragma unroll
            for (int ni = 0; ni < 4; ++ni) {
                int r = wn*64 + ni*16 + lq;
                bf[ni] = *(const short8*)(Bb + r*128 + (((kc*4+g) ^ (r&7))<<4));
            }
            #pragma unroll
            for (int mi = 0; mi < 4; ++mi)
                #pragma unroll
                for (int ni = 0; ni < 4; ++ni)
                    acc[mi][ni] = __builtin_amdgcn_mfma_f32_16x16x32_bf16(
                        af[mi], bf[ni], acc[mi][ni], 0, 0, 0);
        }
        asm volatile("s_waitcnt vmcnt(0)" ::: "memory");
        __builtin_amdgcn_s_barrier();
        asm volatile("" ::: "memory");
        buf ^= 1;
    }
    // -------- epilogue --------
    float bv[4];
    #pragma unroll
    for (int ni = 0; ni < 4; ++ni) bv[ni] = bias[n0 + wn*64 + ni*16 + lq];
    #pragma unroll
    for (int mi = 0; mi < 4; ++mi)
        #pragma unroll
        for (int ni = 0; ni < 4; ++ni)
            #pragma unroll
            for (int i = 0; i < 4; ++i) acc[mi][ni][i] += bv[ni];
    if (MODE == 0) {
        int h = (n0 >> 6) + wn;
        #pragma unroll
        for (int mi = 0; mi < 4; ++mi) {
            f32x4 ss = 0.0f;
            #pragma unroll
            for (int ni = 0; ni < 4; ++ni)
                #pragma unroll
                for (int i = 0; i < 4; ++i) ss[i] += acc[mi][ni][i]*acc[mi][ni][i];
            #pragma unroll
            for (int off = 1; off < 16; off <<= 1)
                #pragma unroll
                for (int i = 0; i < 4; ++i) ss[i] += __shfl_xor(ss[i], off);
            #pragma unroll
            for (int i = 0; i < 4; ++i) {
                float sc = oscale / fmaxf(sqrtf(ss[i]), 1e-12f);
                int m = m0 + wm*64 + mi*16 + g*4 + i;
                int bb = m >> 11, sq = m & (SEQLEN-1);
                unsigned short* orow = (unsigned short*)outp
                    + ((size_t)(bb*NHEADS + h)*SEQLEN + sq)*HEADD;
                #pragma unroll
                for (int ni = 0; ni < 4; ++ni)
                    orow[ni*16 + lq] = f2bf(acc[mi][ni][i] * sc);
            }
        }
    } else if (MODE == 1) {
        int h = (n0 >> 6) + wn;
        #pragma unroll
        for (int mi = 0; mi < 4; ++mi) {
            int m = m0 + wm*64 + mi*16 + g*4;
            int bb = m >> 11, sq = m & (SEQLEN-1);
            #pragma unroll
            for (int ni = 0; ni < 4; ++ni) {
                int d = ni*16 + lq;
                us4v pk;
                #pragma unroll
                for (int i = 0; i < 4; ++i) pk[i] = f2bf(acc[mi][ni][i]);
                *(us4v*)((unsigned short*)outp
                    + ((size_t)(bb*NHEADS + h)*HEADD + d)*SEQLEN + sq) = pk;
            }
        }
    } else {
        #pragma unroll
        for (int mi = 0; mi < 4; ++mi)
            #pragma unroll
            for (int i = 0; i < 4; ++i) {
                int m = m0 + wm*64 + mi*16 + g*4 + i;
                float* orow = (float*)outp + (size_t)m*HDIM;
                const float* rrow = residual + (size_t)m*HDIM;
                #pragma unroll
                for (int ni = 0; ni < 4; ++ni) {
                    int n = n0 + wn*64 + ni*16 + lq;
                    orow[n] = acc[mi][ni][i] + rrow[n];
                }
            }
    }
}

// ---------------- fused 2-step Hopfield attention ----------------
// One wave owns 32 q-rows through BOTH softmax-retrieval steps; state1 never
// leaves registers (cvt_pk + permlane32_swap handoff, same trick as P).
// qg: q bf16 [bh][S][64] pre-scaled by log2e; kg unit rows; vtg V^T [bh][64][S].
// out: bf16 [B][S][H]. lsum computed via ones-MFMA (oL), not VALU adds.
__global__ __launch_bounds__(256, 2) void attn_fused_kernel(
        const unsigned short* __restrict__ qg, const unsigned short* __restrict__ kg,
        const unsigned short* __restrict__ vtg, unsigned short* __restrict__ outp) {
    __shared__ unsigned short L[3][2*4096];   // 48 KiB: 3 × (K 8KB | V 8KB)
    // XCD-bijective swizzle: 4 heads per XCD -> K/V (2MB) stay L2-resident for pass 2
    int b = blockIdx.x;
    int bh = (b & 7)*4 + ((b >> 3) & 3);
    int q0 = (b >> 5) * 128;
    int t = threadIdx.x;
    int wq = t >> 6, l = t & 63;
    int q = l & 31, hi = l >> 5, r7 = q & 7;
    short8 qf[4];
    {
        const unsigned short* qrow = qg + ((size_t)bh*SEQLEN + q0 + wq*32 + q)*HEADD;
        #pragma unroll
        for (int dc = 0; dc < 4; ++dc) qf[dc] = *(const short8*)(qrow + dc*16 + hi*8);
    }
    int koffv[4];
    #pragma unroll
    for (int x = 0; x < 4; ++x) koffv[x] = q*128 + (((x*2 + hi) ^ r7) << 4);
    short8 ones;
    #pragma unroll
    for (int j = 0; j < 8; ++j) ones[j] = (short)0x3F80;   // bf16 1.0

    f32x16 o0 = 0.0f, o1 = 0.0f, oL = 0.0f;
    const unsigned short* Kg = kg + (size_t)bh*SEQLEN*HEADD;
    const unsigned short* Vg = vtg + (size_t)bh*HEADD*SEQLEN;

    // 4 global_load_lds per thread per tile, lane-linear dest (rule 21)
    auto STAGE = [&](int bf, int kt) {
        #pragma unroll
        for (int i = 0; i < 2; ++i) {
            int idx = t + 256*i;
            int r = idx >> 3, ch = idx & 7;
            int gch = ch ^ (r & 7);
            __builtin_amdgcn_global_load_lds(
                (const GLOBAL_AS void*)(Kg + (size_t)(kt*64 + r)*HEADD + gch*8),
                (LDS_AS void*)((char*)&L[bf][0] + idx*16), 16, 0, 0);
            __builtin_amdgcn_global_load_lds(
                (const GLOBAL_AS void*)(Vg + (size_t)r*SEQLEN + kt*64 + gch*8),
                (LDS_AS void*)((char*)&L[bf][0] + 8192 + idx*16), 16, 0, 0);
        }
    };

    const int NT = SEQLEN/64;
    STAGE(0, 0);
    STAGE(1, 1);
    asm volatile("s_waitcnt vmcnt(4)" ::: "memory");   // tile0 ready, tile1 in flight
    __builtin_amdgcn_s_barrier();
    asm volatile("" ::: "memory");
    int cur = 0;
    for (int kt2 = 0; kt2 < 2*NT; ++kt2) {
        if (kt2 + 2 < 2*NT) {
            int pre = cur + 2; if (pre >= 3) pre -= 3;
            STAGE(pre, (kt2 + 2) & (NT-1));
        }
        const char* KL = (const char*)&L[0][0] + cur*16384;
        const char* VL = KL + 8192;
        #pragma unroll
        for (int h = 0; h < 2; ++h) {            // key halves 0-31 / 32-63
            short8 kf[4];
            #pragma unroll
            for (int dc = 0; dc < 4; ++dc)
                kf[dc] = *(const short8*)(KL + koffv[dc] + h*4096);
            f32x16 s = 0.0f;
            __builtin_amdgcn_s_setprio(1);
            #pragma unroll
            for (int dc = 0; dc < 4; ++dc)
                s = __builtin_amdgcn_mfma_f32_32x32x16_bf16(kf[dc], qf[dc], s, 0, 0, 0);
            __builtin_amdgcn_s_setprio(0);
            unsigned int w[8];
            #pragma unroll
            for (int i = 0; i < 8; ++i) {
                float e0 = exp2f(s[2*i]), e1 = exp2f(s[2*i+1]);
                asm("v_cvt_pk_bf16_f32 %0, %1, %2" : "=v"(w[i]) : "v"(e0), "v"(e1));
            }
            asm volatile("v_permlane32_swap_b32 %0, %1" : "+v"(w[0]), "+v"(w[2]));
            asm volatile("v_permlane32_swap_b32 %0, %1" : "+v"(w[1]), "+v"(w[3]));
            asm volatile("v_permlane32_swap_b32 %0, %1" : "+v"(w[4]), "+v"(w[6]));
            asm volatile("v_permlane32_swap_b32 %0, %1" : "+v"(w[5]), "+v"(w[7]));
            #pragma unroll
            for (int c = 0; c < 2; ++c) {
                int j = h*2 + c;
                short8 vf0 = *(const short8*)(VL + koffv[j]);
                short8 vf1 = *(const short8*)(VL + koffv[j] + 4096);
                PW pw;
                pw.u[0] = w[c*4+0]; pw.u[1] = w[c*4+1];
                pw.u[2] = w[c*4+2]; pw.u[3] = w[c*4+3];
                __builtin_amdgcn_s_setprio(1);
                o0 = __builtin_amdgcn_mfma_f32_32x32x16_bf16(vf0, pw.s, o0, 0, 0, 0);
                o1 = __builtin_amdgcn_mfma_f32_32x32x16_bf16(vf1, pw.s, o1, 0, 0, 0);
                oL = __builtin_amdgcn_mfma_f32_32x32x16_bf16(ones, pw.s, oL, 0, 0, 0);
                __builtin_amdgcn_s_setprio(0);
            }
        }
        if (kt2 == NT-1) {
            // ---- pass-0 done: state1 -> new Q fragments, fully in-register ----
            float osc = LOG2E / oL[0];             // every reg of oL == lsum[q]
            unsigned int w0[8], w1[8];
            #pragma unroll
            for (int i = 0; i < 8; ++i) {
                float a0 = o0[2*i]*osc, a1 = o0[2*i+1]*osc;
                asm("v_cvt_pk_bf16_f32 %0, %1, %2" : "=v"(w0[i]) : "v"(a0), "v"(a1));
                float b0 = o1[2*i]*osc, b1 = o1[2*i+1]*osc;
                asm("v_cvt_pk_bf16_f32 %0, %1, %2" : "=v"(w1[i]) : "v"(b0), "v"(b1));
            }
            asm volatile("v_permlane32_swap_b32 %0, %1" : "+v"(w0[0]), "+v"(w0[2]));
            asm volatile("v_permlane32_swap_b32 %0, %1" : "+v"(w0[1]), "+v"(w0[3]));
            asm volatile("v_permlane32_swap_b32 %0, %1" : "+v"(w0[4]), "+v"(w0[6]));
            asm volatile("v_permlane32_swap_b32 %0, %1" : "+v"(w0[5]), "+v"(w0[7]));
            asm volatile("v_permlane32_swap_b32 %0, %1" : "+v"(w1[0]), "+v"(w1[2]));
            asm volatile("v_permlane32_swap_b32 %0, %1" : "+v"(w1[1]), "+v"(w1[3]));
            asm volatile("v_permlane32_swap_b32 %0, %1" : "+v"(w1[4]), "+v"(w1[6]));
            asm volatile("v_permlane32_swap_b32 %0, %1" : "+v"(w1[5]), "+v"(w1[7]));
            PW pa;
            pa.u[0] = w0[0]; pa.u[1] = w0[1]; pa.u[2] = w0[2]; pa.u[3] = w0[3];
            qf[0] = pa.s;
            pa.u[0] = w0[4]; pa.u[1] = w0[5]; pa.u[2] = w0[6]; pa.u[3] = w0[7];
            qf[1] = pa.s;
            pa.u[0] = w1[0]; pa.u[1] = w1[1]; pa.u[2] = w1[2]; pa.u[3] = w1[3];
            qf[2] = pa.s;
            pa.u[0] = w1[4]; pa.u[1] = w1[5]; pa.u[2] = w1[6]; pa.u[3] = w1[7];
            qf[3] = pa.s;
            o0 = 0.0f; o1 = 0.0f; oL = 0.0f;
        }
        if (kt2 + 2 < 2*NT) asm volatile("s_waitcnt vmcnt(4)" ::: "memory");
        else                asm volatile("s_waitcnt vmcnt(0)" ::: "memory");
        __builtin_amdgcn_s_barrier();
        asm volatile("" ::: "memory");
        cur = (cur == 2) ? 0 : cur + 1;
    }
    // ---- final epilogue: out = O / lsum, bf16 [B][S][H] ----
    float osc = 1.0f / oL[0];
    int bb = bh >> 4, hh = bh & 15;
    unsigned short* orow = outp + ((size_t)bb*SEQLEN + q0 + wq*32 + q)*HDIM + hh*HEADD;
    const int dtab[8] = {0,2,8,10,16,18,24,26};
    #pragma unroll
    for (int i = 0; i < 8; ++i) {
        int d = dtab[i] + 4*hi;
        unsigned int wv;
        float a0 = o0[2*i]*osc, a1 = o0[2*i+1]*osc;
        asm("v_cvt_pk_bf16_f32 %0, %1, %2" : "=v"(wv) : "v"(a0), "v"(a1));
        *(unsigned int*)(orow + d) = wv;
        float c0 = o1[2*i]*osc, c1 = o1[2*i+1]*osc;
        asm("v_cvt_pk_bf16_f32 %0, %1, %2" : "=v"(wv) : "v"(c0), "v"(c1));
        *(unsigned int*)(orow + 32 + d) = wv;
    }
}

extern "C" void kernel_launch(void* const* d_in, const int* in_sizes, int n_in,
                              void* d_out, int out_size, void* d_ws, size_t ws_size,
                              hipStream_t stream) {
    const float* hs = (const float*)d_in[0];
    const float* Wq = (const float*)d_in[1];
    const float* bq = (const float*)d_in[2];
    const float* Wk = (const float*)d_in[3];
    const float* bk = (const float*)d_in[4];
    const float* Wv = (const float*)d_in[5];
    const float* bv = (const float*)d_in[6];
    const float* Wo = (const float*)d_in[7];
    const float* bo = (const float*)d_in[8];
    const float* lw = (const float*)d_in[9];
    const float* lb = (const float*)d_in[10];
    unsigned short* ws16 = (unsigned short*)d_ws;
    const size_t NE = (size_t)NROWS * HDIM;
    const size_t WE = (size_t)HDIM * HDIM;
    unsigned short* xn  = ws16;
    unsigned short* Wtq = xn + NE;
    unsigned short* Wtk = Wtq + WE;
    unsigned short* Wtv = Wtk + WE;
    unsigned short* Wto = Wtv + WE;
    unsigned short* qb  = Wto + WE;
    unsigned short* kb  = qb + NE;
    unsigned short* vt  = kb + NE;
    unsigned short* s2  = vt + NE;

    ln_kernel<<<NROWS, 256, 0, stream>>>(hs, lw, lb, xn);
    dim3 wg(HDIM/64, HDIM/64);
    wconv_kernel<<<wg, 256, 0, stream>>>(Wq, Wtq);
    wconv_kernel<<<wg, 256, 0, stream>>>(Wk, Wtk);
    wconv_kernel<<<wg, 256, 0, stream>>>(Wv, Wtv);
    wconv_kernel<<<wg, 256, 0, stream>>>(Wo, Wto);
    dim3 gg(NROWS/128, HDIM/128);
    // q pre-scaled by log2e (exp2-domain softmax); k unit-normalized
    gemm_mfma_kernel<0><<<gg, 256, 0, stream>>>(xn, Wtq, bq, nullptr, qb, LOG2E);
    gemm_mfma_kernel<0><<<gg, 256, 0, stream>>>(xn, Wtk, bk, nullptr, kb, 1.0f);
    gemm_mfma_kernel<1><<<gg, 256, 0, stream>>>(xn, Wtv, bv, nullptr, vt, 1.0f);
    attn_fused_kernel<<<NBH*16, 256, 0, stream>>>(qb, kb, vt, s2);
    gemm_mfma_kernel<2><<<gg, 256, 0, stream>>>(s2, Wto, bo, hs, (void*)d_out, 1.0f);
}

// Round 8
// 208.415 us; speedup vs baseline: 1.2494x; 1.0550x over previous
//
#include <hip/hip_runtime.h>
#include <hip/hip_bf16.h>
#include <math.h>

#define HDIM 1024
#define NHEADS 16
#define HEADD 64
#define SEQLEN 2048
#define NBATCH 2
#define NROWS (NBATCH*SEQLEN)
#define NBH (NBATCH*NHEADS)
#define LOG2E 1.44269504f

typedef float f32x4 __attribute__((ext_vector_type(4)));
typedef float f32x16 __attribute__((ext_vector_type(16)));
typedef short short8 __attribute__((ext_vector_type(8)));
typedef unsigned short us4v __attribute__((ext_vector_type(4)));

#define GLOBAL_AS __attribute__((address_space(1)))
#define LDS_AS __attribute__((address_space(3)))

union F4 { float4 v; float f[4]; };
union PW { unsigned int u[4]; short8 s; };

static __device__ __forceinline__ unsigned short f2bf(float x) {
    __hip_bfloat16 h = __float2bfloat16(x);
    return *(unsigned short*)&h;
}

// ---------------- LayerNorm -> bf16 ----------------
__global__ __launch_bounds__(256) void ln_kernel(
        const float* __restrict__ x, const float* __restrict__ w,
        const float* __restrict__ b, unsigned short* __restrict__ xn) {
    int row = blockIdx.x;
    F4 vv; vv.v = ((const float4*)(x + (size_t)row*HDIM))[threadIdx.x];
    float s  = vv.f[0]+vv.f[1]+vv.f[2]+vv.f[3];
    float ss = vv.f[0]*vv.f[0]+vv.f[1]*vv.f[1]+vv.f[2]*vv.f[2]+vv.f[3]*vv.f[3];
    #pragma unroll
    for (int off = 32; off > 0; off >>= 1) {
        s  += __shfl_xor(s, off);
        ss += __shfl_xor(ss, off);
    }
    __shared__ float red[8];
    int wid = threadIdx.x >> 6;
    if ((threadIdx.x & 63) == 0) { red[wid] = s; red[wid+4] = ss; }
    __syncthreads();
    s  = red[0]+red[1]+red[2]+red[3];
    ss = red[4]+red[5]+red[6]+red[7];
    float mean = s * (1.0f/HDIM);
    float var  = ss * (1.0f/HDIM) - mean*mean;
    float rstd = rsqrtf(var + 1e-5f);
    F4 wv; wv.v = ((const float4*)w)[threadIdx.x];
    F4 bv; bv.v = ((const float4*)b)[threadIdx.x];
    us4v o;
    #pragma unroll
    for (int j = 0; j < 4; ++j)
        o[j] = f2bf((vv.f[j]-mean)*rstd*wv.f[j] + bv.f[j]);
    *(us4v*)(xn + (size_t)row*HDIM + threadIdx.x*4) = o;
}

// ---------- weight convert+transpose: W[k][n] f32 -> Wt[n][k] bf16 ----------
__global__ __launch_bounds__(256) void wconv_kernel(
        const float* __restrict__ W, unsigned short* __restrict__ Wt) {
    __shared__ unsigned short T[64*72];
    int k0 = blockIdx.x*64, n0 = blockIdx.y*64;
    int t = threadIdx.x;
    #pragma unroll
    for (int it = 0; it < 4; ++it) {
        int r = (t>>4) + it*16;
        int c = (t&15)*4;
        F4 x; x.v = *(const float4*)(W + (size_t)(k0+r)*HDIM + n0 + c);
        #pragma unroll
        for (int j = 0; j < 4; ++j) T[(c+j)*72 + r] = f2bf(x.f[j]);
    }
    __syncthreads();
    #pragma unroll
    for (int it = 0; it < 2; ++it) {
        int n = (t>>3) + it*32;
        int ch = t&7;
        short8 rowv = *(const short8*)(T + n*72 + ch*8);
        *(short8*)(Wt + (size_t)(n0+n)*HDIM + k0 + ch*8) = rowv;
    }
}

// ---------------- bf16 MFMA GEMM: C = A @ Wt^T (+bias), 2-phase dbuf ----------------
template<int MODE>
__global__ __launch_bounds__(256) void gemm_mfma_kernel(
        const unsigned short* __restrict__ A,
        const unsigned short* __restrict__ Wt,
        const float* __restrict__ bias,
        const float* __restrict__ residual,
        void* __restrict__ outp, float oscale) {
    __shared__ unsigned short As[2][128*64];
    __shared__ unsigned short Bs[2][128*64];
    int m0 = blockIdx.x * 128;
    int n0 = blockIdx.y * 128;
    int t = threadIdx.x;
    int wid = t >> 6, l = t & 63;
    int wm = wid >> 1, wn = wid & 1;
    int lq = l & 15, g = l >> 4;
    f32x4 acc[4][4];
    #pragma unroll
    for (int mi = 0; mi < 4; ++mi)
        #pragma unroll
        for (int ni = 0; ni < 4; ++ni) acc[mi][ni] = 0.0f;

    auto STAGE = [&](int b, int k0) {
        #pragma unroll
        for (int i = 0; i < 4; ++i) {
            int idx = t + 256*i;
            int r = idx >> 3, ch = idx & 7;
            int gch = ch ^ (r & 7);
            __builtin_amdgcn_global_load_lds(
                (const GLOBAL_AS void*)(A + (size_t)(m0+r)*HDIM + k0 + gch*8),
                (LDS_AS void*)((char*)&As[b][0] + idx*16), 16, 0, 0);
            __builtin_amdgcn_global_load_lds(
                (const GLOBAL_AS void*)(Wt + (size_t)(n0+r)*HDIM + k0 + gch*8),
                (LDS_AS void*)((char*)&Bs[b][0] + idx*16), 16, 0, 0);
        }
    };

    STAGE(0, 0);
    asm volatile("s_waitcnt vmcnt(0)" ::: "memory");
    __builtin_amdgcn_s_barrier();
    asm volatile("" ::: "memory");
    int buf = 0;
    for (int ks = 0; ks < 16; ++ks) {
        if (ks < 15) STAGE(buf^1, (ks+1)*64);
        const char* Ab = (const char*)&As[buf][0];
        const char* Bb = (const char*)&Bs[buf][0];
        #pragma unroll
        for (int kc = 0; kc < 2; ++kc) {
            short8 af[4], bf[4];
            #pragma unroll
            for (int mi = 0; mi < 4; ++mi) {
                int r = wm*64 + mi*16 + lq;
                af[mi] = *(const short8*)(Ab + r*128 + (((kc*4+g) ^ (r&7))<<4));
            }
            #pragma unroll
            for (int ni = 0; ni < 4; ++ni) {
                int r = wn*64 + ni*16 + lq;
                bf[ni] = *(const short8*)(Bb + r*128 + (((kc*4+g) ^ (r&7))<<4));
            }
            #pragma unroll
            for (int mi = 0; mi < 4; ++mi)
                #pragma unroll
                for (int ni = 0; ni < 4; ++ni)
                    acc[mi][ni] = __builtin_amdgcn_mfma_f32_16x16x32_bf16(
                        af[mi], bf[ni], acc[mi][ni], 0, 0, 0);
        }
        asm volatile("s_waitcnt vmcnt(0)" ::: "memory");
        __builtin_amdgcn_s_barrier();
        asm volatile("" ::: "memory");
        buf ^= 1;
    }
    // -------- epilogue --------
    float bv[4];
    #pragma unroll
    for (int ni = 0; ni < 4; ++ni) bv[ni] = bias[n0 + wn*64 + ni*16 + lq];
    #pragma unroll
    for (int mi = 0; mi < 4; ++mi)
        #pragma unroll
        for (int ni = 0; ni < 4; ++ni)
            #pragma unroll
            for (int i = 0; i < 4; ++i) acc[mi][ni][i] += bv[ni];
    if (MODE == 0) {
        int h = (n0 >> 6) + wn;
        #pragma unroll
        for (int mi = 0; mi < 4; ++mi) {
            f32x4 ss = 0.0f;
            #pragma unroll
            for (int ni = 0; ni < 4; ++ni)
                #pragma unroll
                for (int i = 0; i < 4; ++i) ss[i] += acc[mi][ni][i]*acc[mi][ni][i];
            #pragma unroll
            for (int off = 1; off < 16; off <<= 1)
                #pragma unroll
                for (int i = 0; i < 4; ++i) ss[i] += __shfl_xor(ss[i], off);
            #pragma unroll
            for (int i = 0; i < 4; ++i) {
                float sc = oscale / fmaxf(sqrtf(ss[i]), 1e-12f);
                int m = m0 + wm*64 + mi*16 + g*4 + i;
                int bb = m >> 11, sq = m & (SEQLEN-1);
                unsigned short* orow = (unsigned short*)outp
                    + ((size_t)(bb*NHEADS + h)*SEQLEN + sq)*HEADD;
                #pragma unroll
                for (int ni = 0; ni < 4; ++ni)
                    orow[ni*16 + lq] = f2bf(acc[mi][ni][i] * sc);
            }
        }
    } else if (MODE == 1) {
        int h = (n0 >> 6) + wn;
        #pragma unroll
        for (int mi = 0; mi < 4; ++mi) {
            int m = m0 + wm*64 + mi*16 + g*4;
            int bb = m >> 11, sq = m & (SEQLEN-1);
            #pragma unroll
            for (int ni = 0; ni < 4; ++ni) {
                int d = ni*16 + lq;
                us4v pk;
                #pragma unroll
                for (int i = 0; i < 4; ++i) pk[i] = f2bf(acc[mi][ni][i]);
                *(us4v*)((unsigned short*)outp
                    + ((size_t)(bb*NHEADS + h)*HEADD + d)*SEQLEN + sq) = pk;
            }
        }
    } else {
        #pragma unroll
        for (int mi = 0; mi < 4; ++mi)
            #pragma unroll
            for (int i = 0; i < 4; ++i) {
                int m = m0 + wm*64 + mi*16 + g*4 + i;
                float* orow = (float*)outp + (size_t)m*HDIM;
                const float* rrow = residual + (size_t)m*HDIM;
                #pragma unroll
                for (int ni = 0; ni < 4; ++ni) {
                    int n = n0 + wn*64 + ni*16 + lq;
                    orow[n] = acc[mi][ni][i] + rrow[n];
                }
            }
    }
}

// ---------------- fused 2-step Hopfield attention, key-split waves ----------------
// 512-thread blocks, 8 waves = 4 q-groups (wq) x 2 key-halves (ks).
// Wave (wq,ks): 32 q-rows, keys ks*32..+31 of each 64-key tile.
// Partials combined via LDS at pass boundary + end; state1 handoff in-register.
// qg pre-scaled by log2e; exp via raw v_exp_f32.
#define SLOFF 49152          // combine area after 3 staging buffers
#define SLSZ  4352           // per-wq slot: 16x64 u32 (4KB) + 64 f32 lsum
__global__ __launch_bounds__(512, 4) void attn_fused_kernel(
        const unsigned short* __restrict__ qg, const unsigned short* __restrict__ kg,
        const unsigned short* __restrict__ vtg, unsigned short* __restrict__ outp) {
    __shared__ char L[SLOFF + 4*SLSZ];   // 48KB staging + 17KB combine
    int b = blockIdx.x;
    int bh = (b & 7)*4 + ((b >> 3) & 3);   // 4 heads per XCD
    int q0 = (b >> 5) * 128;               // 128 q-rows per block
    int t = threadIdx.x;
    int wid = t >> 6, l = t & 63;
    int wq = wid >> 1, ks = wid & 1;
    int q = l & 31, hi = l >> 5, r7 = q & 7;
    short8 qf[4];
    {
        const unsigned short* qrow = qg + ((size_t)bh*SEQLEN + q0 + wq*32 + q)*HEADD;
        #pragma unroll
        for (int dc = 0; dc < 4; ++dc) qf[dc] = *(const short8*)(qrow + dc*16 + hi*8);
    }
    int koffv[4];
    #pragma unroll
    for (int x = 0; x < 4; ++x) koffv[x] = q*128 + (((x*2 + hi) ^ r7) << 4);
    short8 ones;
    #pragma unroll
    for (int j = 0; j < 8; ++j) ones[j] = (short)0x3F80;

    f32x16 o0 = 0.0f, o1 = 0.0f, oL = 0.0f;
    const unsigned short* Kg = kg + (size_t)bh*SEQLEN*HEADD;
    const unsigned short* Vg = vtg + (size_t)bh*HEADD*SEQLEN;
    unsigned int* slot = (unsigned int*)(L + SLOFF + wq*SLSZ);
    float* slsum = (float*)(L + SLOFF + wq*SLSZ + 4096);

    // 2 loads/thread/tile, lane-linear dest (rule 21)
    auto STAGE = [&](int bf, int kt) {
        int r = t >> 3, ch = t & 7;
        int gch = ch ^ (r & 7);
        __builtin_amdgcn_global_load_lds(
            (const GLOBAL_AS void*)(Kg + (size_t)(kt*64 + r)*HEADD + gch*8),
            (LDS_AS void*)(L + bf*16384 + t*16), 16, 0, 0);
        __builtin_amdgcn_global_load_lds(
            (const GLOBAL_AS void*)(Vg + (size_t)r*SEQLEN + kt*64 + gch*8),
            (LDS_AS void*)(L + bf*16384 + 8192 + t*16), 16, 0, 0);
    };

    const int NT = SEQLEN/64;
    STAGE(0, 0);
    STAGE(1, 1);
    asm volatile("s_waitcnt vmcnt(2)" ::: "memory");
    __builtin_amdgcn_s_barrier();
    asm volatile("" ::: "memory");
    int cur = 0;
    for (int kt2 = 0; kt2 < 2*NT; ++kt2) {
        if (kt2 + 2 < 2*NT) {
            int pre = cur + 2; if (pre >= 3) pre -= 3;
            STAGE(pre, (kt2 + 2) & (NT-1));
        }
        const char* KL = L + cur*16384 + ks*4096;   // this wave's key-half
        const char* VL = L + cur*16384 + 8192;
        short8 kf[4];
        #pragma unroll
        for (int dc = 0; dc < 4; ++dc)
            kf[dc] = *(const short8*)(KL + koffv[dc]);
        f32x16 s = 0.0f;
        __builtin_amdgcn_s_setprio(1);
        #pragma unroll
        for (int dc = 0; dc < 4; ++dc)
            s = __builtin_amdgcn_mfma_f32_32x32x16_bf16(kf[dc], qf[dc], s, 0, 0, 0);
        __builtin_amdgcn_s_setprio(0);
        unsigned int w[8];
        #pragma unroll
        for (int i = 0; i < 8; ++i) {
            float e0 = __builtin_amdgcn_exp2f(s[2*i]);
            float e1 = __builtin_amdgcn_exp2f(s[2*i+1]);
            asm("v_cvt_pk_bf16_f32 %0, %1, %2" : "=v"(w[i]) : "v"(e0), "v"(e1));
        }
        asm volatile("v_permlane32_swap_b32 %0, %1" : "+v"(w[0]), "+v"(w[2]));
        asm volatile("v_permlane32_swap_b32 %0, %1" : "+v"(w[1]), "+v"(w[3]));
        asm volatile("v_permlane32_swap_b32 %0, %1" : "+v"(w[4]), "+v"(w[6]));
        asm volatile("v_permlane32_swap_b32 %0, %1" : "+v"(w[5]), "+v"(w[7]));
        #pragma unroll
        for (int c = 0; c < 2; ++c) {
            int j = ks*2 + c;                 // key 16-slice index in tile
            short8 vf0 = *(const short8*)(VL + koffv[j]);
            short8 vf1 = *(const short8*)(VL + koffv[j] + 4096);
            PW pw;
            pw.u[0] = w[c*4+0]; pw.u[1] = w[c*4+1];
            pw.u[2] = w[c*4+2]; pw.u[3] = w[c*4+3];
            __builtin_amdgcn_s_setprio(1);
            o0 = __builtin_amdgcn_mfma_f32_32x32x16_bf16(vf0, pw.s, o0, 0, 0, 0);
            o1 = __builtin_amdgcn_mfma_f32_32x32x16_bf16(vf1, pw.s, o1, 0, 0, 0);
            oL = __builtin_amdgcn_mfma_f32_32x32x16_bf16(ones, pw.s, oL, 0, 0, 0);
            __builtin_amdgcn_s_setprio(0);
        }
        if (kt2 == NT-1 && ks == 1) {
            // write partial O (packed bf16) + partial lsum for combine
            #pragma unroll
            for (int i = 0; i < 8; ++i) {
                unsigned int u;
                asm("v_cvt_pk_bf16_f32 %0, %1, %2" : "=v"(u) : "v"(o0[2*i]), "v"(o0[2*i+1]));
                slot[i*64 + l] = u;
                asm("v_cvt_pk_bf16_f32 %0, %1, %2" : "=v"(u) : "v"(o1[2*i]), "v"(o1[2*i+1]));
                slot[(8+i)*64 + l] = u;
            }
            slsum[l] = oL[0];
            asm volatile("s_waitcnt lgkmcnt(0)" ::: "memory");
        }
        if (kt2 + 2 < 2*NT) asm volatile("s_waitcnt vmcnt(2)" ::: "memory");
        else                asm volatile("s_waitcnt vmcnt(0)" ::: "memory");
        __builtin_amdgcn_s_barrier();
        asm volatile("" ::: "memory");
        if (kt2 == NT-1) {
            // ---- pass boundary: combine halves, compute state1, share qf ----
            if (ks == 0) {
                #pragma unroll
                for (int i = 0; i < 8; ++i) {
                    unsigned int u = slot[i*64 + l];
                    o0[2*i]   += __uint_as_float(u << 16);
                    o0[2*i+1] += __uint_as_float(u & 0xffff0000u);
                    u = slot[(8+i)*64 + l];
                    o1[2*i]   += __uint_as_float(u << 16);
                    o1[2*i+1] += __uint_as_float(u & 0xffff0000u);
                }
                float osc = LOG2E / (oL[0] + slsum[l]);
                unsigned int w0[8], w1[8];
                #pragma unroll
                for (int i = 0; i < 8; ++i) {
                    float a0 = o0[2*i]*osc, a1 = o0[2*i+1]*osc;
                    asm("v_cvt_pk_bf16_f32 %0, %1, %2" : "=v"(w0[i]) : "v"(a0), "v"(a1));
                    float b0 = o1[2*i]*osc, b1 = o1[2*i+1]*osc;
                    asm("v_cvt_pk_bf16_f32 %0, %1, %2" : "=v"(w1[i]) : "v"(b0), "v"(b1));
                }
                asm volatile("v_permlane32_swap_b32 %0, %1" : "+v"(w0[0]), "+v"(w0[2]));
                asm volatile("v_permlane32_swap_b32 %0, %1" : "+v"(w0[1]), "+v"(w0[3]));
                asm volatile("v_permlane32_swap_b32 %0, %1" : "+v"(w0[4]), "+v"(w0[6]));
                asm volatile("v_permlane32_swap_b32 %0, %1" : "+v"(w0[5]), "+v"(w0[7]));
                asm volatile("v_permlane32_swap_b32 %0, %1" : "+v"(w1[0]), "+v"(w1[2]));
                asm volatile("v_permlane32_swap_b32 %0, %1" : "+v"(w1[1]), "+v"(w1[3]));
                asm volatile("v_permlane32_swap_b32 %0, %1" : "+v"(w1[4]), "+v"(w1[6]));
                asm volatile("v_permlane32_swap_b32 %0, %1" : "+v"(w1[5]), "+v"(w1[7]));
                PW pa;
                pa.u[0]=w0[0]; pa.u[1]=w0[1]; pa.u[2]=w0[2]; pa.u[3]=w0[3]; qf[0]=pa.s;
                pa.u[0]=w0[4]; pa.u[1]=w0[5]; pa.u[2]=w0[6]; pa.u[3]=w0[7]; qf[1]=pa.s;
                pa.u[0]=w1[0]; pa.u[1]=w1[1]; pa.u[2]=w1[2]; pa.u[3]=w1[3]; qf[2]=pa.s;
                pa.u[0]=w1[4]; pa.u[1]=w1[5]; pa.u[2]=w1[6]; pa.u[3]=w1[7]; qf[3]=pa.s;
                #pragma unroll
                for (int i = 0; i < 8; ++i) {
                    slot[i*64 + l] = w0[i];
                    slot[(8+i)*64 + l] = w1[i];
                }
                asm volatile("s_waitcnt lgkmcnt(0)" ::: "memory");
            }
            __builtin_amdgcn_s_barrier();
            asm volatile("" ::: "memory");
            if (ks == 1) {
                PW pa;
                pa.u[0]=slot[0*64+l]; pa.u[1]=slot[1*64+l]; pa.u[2]=slot[2*64+l]; pa.u[3]=slot[3*64+l]; qf[0]=pa.s;
                pa.u[0]=slot[4*64+l]; pa.u[1]=slot[5*64+l]; pa.u[2]=slot[6*64+l]; pa.u[3]=slot[7*64+l]; qf[1]=pa.s;
                pa.u[0]=slot[8*64+l]; pa.u[1]=slot[9*64+l]; pa.u[2]=slot[10*64+l]; pa.u[3]=slot[11*64+l]; qf[2]=pa.s;
                pa.u[0]=slot[12*64+l]; pa.u[1]=slot[13*64+l]; pa.u[2]=slot[14*64+l]; pa.u[3]=slot[15*64+l]; qf[3]=pa.s;
            }
            o0 = 0.0f; o1 = 0.0f; oL = 0.0f;
        }
        cur = (cur == 2) ? 0 : cur + 1;
    }
    // ---- final combine + output ----
    if (ks == 1) {
        #pragma unroll
        for (int i = 0; i < 8; ++i) {
            unsigned int u;
            asm("v_cvt_pk_bf16_f32 %0, %1, %2" : "=v"(u) : "v"(o0[2*i]), "v"(o0[2*i+1]));
            slot[i*64 + l] = u;
            asm("v_cvt_pk_bf16_f32 %0, %1, %2" : "=v"(u) : "v"(o1[2*i]), "v"(o1[2*i+1]));
            slot[(8+i)*64 + l] = u;
        }
        slsum[l] = oL[0];
        asm volatile("s_waitcnt lgkmcnt(0)" ::: "memory");
    }
    __builtin_amdgcn_s_barrier();
    asm volatile("" ::: "memory");
    if (ks == 0) {
        #pragma unroll
        for (int i = 0; i < 8; ++i) {
            unsigned int u = slot[i*64 + l];
            o0[2*i]   += __uint_as_float(u << 16);
            o0[2*i+1] += __uint_as_float(u & 0xffff0000u);
            u = slot[(8+i)*64 + l];
            o1[2*i]   += __uint_as_float(u << 16);
            o1[2*i+1] += __uint_as_float(u & 0xffff0000u);
        }
        float osc = 1.0f / (oL[0] + slsum[l]);
        int bb = bh >> 4, hh = bh & 15;
        unsigned short* orow = outp + ((size_t)bb*SEQLEN + q0 + wq*32 + q)*HDIM + hh*HEADD;
        const int dtab[8] = {0,2,8,10,16,18,24,26};
        #pragma unroll
        for (int i = 0; i < 8; ++i) {
            int d = dtab[i] + 4*hi;
            unsigned int wv;
            float a0 = o0[2*i]*osc, a1 = o0[2*i+1]*osc;
            asm("v_cvt_pk_bf16_f32 %0, %1, %2" : "=v"(wv) : "v"(a0), "v"(a1));
            *(unsigned int*)(orow + d) = wv;
            float c0 = o1[2*i]*osc, c1 = o1[2*i+1]*osc;
            asm("v_cvt_pk_bf16_f32 %0, %1, %2" : "=v"(wv) : "v"(c0), "v"(c1));
            *(unsigned int*)(orow + 32 + d) = wv;
        }
    }
}

extern "C" void kernel_launch(void* const* d_in, const int* in_sizes, int n_in,
                              void* d_out, int out_size, void* d_ws, size_t ws_size,
                              hipStream_t stream) {
    const float* hs = (const float*)d_in[0];
    const float* Wq = (const float*)d_in[1];
    const float* bq = (const float*)d_in[2];
    const float* Wk = (const float*)d_in[3];
    const float* bk = (const float*)d_in[4];
    const float* Wv = (const float*)d_in[5];
    const float* bv = (const float*)d_in[6];
    const float* Wo = (const float*)d_in[7];
    const float* bo = (const float*)d_in[8];
    const float* lw = (const float*)d_in[9];
    const float* lb = (const float*)d_in[10];
    unsigned short* ws16 = (unsigned short*)d_ws;
    const size_t NE = (size_t)NROWS * HDIM;
    const size_t WE = (size_t)HDIM * HDIM;
    unsigned short* xn  = ws16;
    unsigned short* Wtq = xn + NE;
    unsigned short* Wtk = Wtq + WE;
    unsigned short* Wtv = Wtk + WE;
    unsigned short* Wto = Wtv + WE;
    unsigned short* qb  = Wto + WE;
    unsigned short* kb  = qb + NE;
    unsigned short* vt  = kb + NE;
    unsigned short* s2  = vt + NE;

    ln_kernel<<<NROWS, 256, 0, stream>>>(hs, lw, lb, xn);
    dim3 wg(HDIM/64, HDIM/64);
    wconv_kernel<<<wg, 256, 0, stream>>>(Wq, Wtq);
    wconv_kernel<<<wg, 256, 0, stream>>>(Wk, Wtk);
    wconv_kernel<<<wg, 256, 0, stream>>>(Wv, Wtv);
    wconv_kernel<<<wg, 256, 0, stream>>>(Wo, Wto);
    dim3 gg(NROWS/128, HDIM/128);
    gemm_mfma_kernel<0><<<gg, 256, 0, stream>>>(xn, Wtq, bq, nullptr, qb, LOG2E);
    gemm_mfma_kernel<0><<<gg, 256, 0, stream>>>(xn, Wtk, bk, nullptr, kb, 1.0f);
    gemm_mfma_kernel<1><<<gg, 256, 0, stream>>>(xn, Wtv, bv, nullptr, vt, 1.0f);
    attn_fused_kernel<<<NBH*16, 512, 0, stream>>>(qb, kb, vt, s2);
    gemm_mfma_kernel<2><<<gg, 256, 0, stream>>>(s2, Wto, bo, hs, (void*)d_out, 1.0f);
}

// Round 9
// 185.949 us; speedup vs baseline: 1.4004x; 1.1208x over previous
//
#include <hip/hip_runtime.h>
#include <hip/hip_bf16.h>
#include <math.h>

#define HDIM 1024
#define NHEADS 16
#define HEADD 64
#define SEQLEN 2048
#define NBATCH 2
#define NROWS (NBATCH*SEQLEN)
#define NBH (NBATCH*NHEADS)
#define LOG2E 1.44269504f
#define NT 32   // 64-key tiles per pass

typedef float f32x4 __attribute__((ext_vector_type(4)));
typedef float f32x16 __attribute__((ext_vector_type(16)));
typedef short short8 __attribute__((ext_vector_type(8)));
typedef unsigned short us4v __attribute__((ext_vector_type(4)));

#define GLOBAL_AS __attribute__((address_space(1)))
#define LDS_AS __attribute__((address_space(3)))

union F4 { float4 v; float f[4]; };
union PW { unsigned int u[4]; short8 s; };

static __device__ __forceinline__ unsigned short f2bf(float x) {
    __hip_bfloat16 h = __float2bfloat16(x);
    return *(unsigned short*)&h;
}

// ---------------- LayerNorm -> bf16 ----------------
__global__ __launch_bounds__(256) void ln_kernel(
        const float* __restrict__ x, const float* __restrict__ w,
        const float* __restrict__ b, unsigned short* __restrict__ xn) {
    int row = blockIdx.x;
    F4 vv; vv.v = ((const float4*)(x + (size_t)row*HDIM))[threadIdx.x];
    float s  = vv.f[0]+vv.f[1]+vv.f[2]+vv.f[3];
    float ss = vv.f[0]*vv.f[0]+vv.f[1]*vv.f[1]+vv.f[2]*vv.f[2]+vv.f[3]*vv.f[3];
    #pragma unroll
    for (int off = 32; off > 0; off >>= 1) {
        s  += __shfl_xor(s, off);
        ss += __shfl_xor(ss, off);
    }
    __shared__ float red[8];
    int wid = threadIdx.x >> 6;
    if ((threadIdx.x & 63) == 0) { red[wid] = s; red[wid+4] = ss; }
    __syncthreads();
    s  = red[0]+red[1]+red[2]+red[3];
    ss = red[4]+red[5]+red[6]+red[7];
    float mean = s * (1.0f/HDIM);
    float var  = ss * (1.0f/HDIM) - mean*mean;
    float rstd = rsqrtf(var + 1e-5f);
    F4 wv; wv.v = ((const float4*)w)[threadIdx.x];
    F4 bv; bv.v = ((const float4*)b)[threadIdx.x];
    us4v o;
    #pragma unroll
    for (int j = 0; j < 4; ++j)
        o[j] = f2bf((vv.f[j]-mean)*rstd*wv.f[j] + bv.f[j]);
    *(us4v*)(xn + (size_t)row*HDIM + threadIdx.x*4) = o;
}

// ---------- weight convert+transpose (all 4 in one launch, z=matrix) ----------
__global__ __launch_bounds__(256) void wconv_kernel(
        const float* __restrict__ W0, const float* __restrict__ W1,
        const float* __restrict__ W2, const float* __restrict__ W3,
        unsigned short* __restrict__ WtBase) {
    __shared__ unsigned short T[64*72];
    int z = blockIdx.z;
    const float* W = (z == 0) ? W0 : (z == 1) ? W1 : (z == 2) ? W2 : W3;
    unsigned short* Wt = WtBase + (size_t)z*HDIM*HDIM;
    int k0 = blockIdx.x*64, n0 = blockIdx.y*64;
    int t = threadIdx.x;
    #pragma unroll
    for (int it = 0; it < 4; ++it) {
        int r = (t>>4) + it*16;
        int c = (t&15)*4;
        F4 x; x.v = *(const float4*)(W + (size_t)(k0+r)*HDIM + n0 + c);
        #pragma unroll
        for (int j = 0; j < 4; ++j) T[(c+j)*72 + r] = f2bf(x.f[j]);
    }
    __syncthreads();
    #pragma unroll
    for (int it = 0; it < 2; ++it) {
        int n = (t>>3) + it*32;
        int ch = t&7;
        short8 rowv = *(const short8*)(T + n*72 + ch*8);
        *(short8*)(Wt + (size_t)(n0+n)*HDIM + k0 + ch*8) = rowv;
    }
}

// ------------- fused QKV GEMM: mat = blockIdx.y>>3 (0:Q 1:K 2:V) -------------
// Q/K: +bias, L2-normalize rows per head (Q also ×log2e), bf16 head-major
// V:   +bias, bf16 transposed [bh][64][s]
__global__ __launch_bounds__(256) void gemm_qkv_kernel(
        const unsigned short* __restrict__ A,
        const unsigned short* __restrict__ WtBase,
        const float* __restrict__ bq, const float* __restrict__ bk,
        const float* __restrict__ bv,
        unsigned short* __restrict__ qb, unsigned short* __restrict__ kb,
        unsigned short* __restrict__ vt) {
    __shared__ unsigned short As[2][128*64];
    __shared__ unsigned short Bs[2][128*64];
    int m0 = blockIdx.x * 128;
    int yy = blockIdx.y;
    int mat = yy >> 3;
    int n0 = (yy & 7) * 128;
    const unsigned short* Wt = WtBase + (size_t)mat*HDIM*HDIM;
    const float* bias = (mat == 0) ? bq : (mat == 1) ? bk : bv;
    int t = threadIdx.x;
    int wid = t >> 6, l = t & 63;
    int wm = wid >> 1, wn = wid & 1;
    int lq = l & 15, g = l >> 4;
    f32x4 acc[4][4];
    #pragma unroll
    for (int mi = 0; mi < 4; ++mi)
        #pragma unroll
        for (int ni = 0; ni < 4; ++ni) acc[mi][ni] = 0.0f;

    auto STAGE = [&](int b, int k0) {
        #pragma unroll
        for (int i = 0; i < 4; ++i) {
            int idx = t + 256*i;
            int r = idx >> 3, ch = idx & 7;
            int gch = ch ^ (r & 7);
            __builtin_amdgcn_global_load_lds(
                (const GLOBAL_AS void*)(A + (size_t)(m0+r)*HDIM + k0 + gch*8),
                (LDS_AS void*)((char*)&As[b][0] + idx*16), 16, 0, 0);
            __builtin_amdgcn_global_load_lds(
                (const GLOBAL_AS void*)(Wt + (size_t)(n0+r)*HDIM + k0 + gch*8),
                (LDS_AS void*)((char*)&Bs[b][0] + idx*16), 16, 0, 0);
        }
    };

    STAGE(0, 0);
    asm volatile("s_waitcnt vmcnt(0)" ::: "memory");
    __builtin_amdgcn_s_barrier();
    asm volatile("" ::: "memory");
    int buf = 0;
    for (int ks = 0; ks < 16; ++ks) {
        if (ks < 15) STAGE(buf^1, (ks+1)*64);
        const char* Ab = (const char*)&As[buf][0];
        const char* Bb = (const char*)&Bs[buf][0];
        #pragma unroll
        for (int kc = 0; kc < 2; ++kc) {
            short8 af[4], bf[4];
            #pragma unroll
            for (int mi = 0; mi < 4; ++mi) {
                int r = wm*64 + mi*16 + lq;
                af[mi] = *(const short8*)(Ab + r*128 + (((kc*4+g) ^ (r&7))<<4));
            }
            #pragma unroll
            for (int ni = 0; ni < 4; ++ni) {
                int r = wn*64 + ni*16 + lq;
                bf[ni] = *(const short8*)(Bb + r*128 + (((kc*4+g) ^ (r&7))<<4));
            }
            #pragma unroll
            for (int mi = 0; mi < 4; ++mi)
                #pragma unroll
                for (int ni = 0; ni < 4; ++ni)
                    acc[mi][ni] = __builtin_amdgcn_mfma_f32_16x16x32_bf16(
                        af[mi], bf[ni], acc[mi][ni], 0, 0, 0);
        }
        asm volatile("s_waitcnt vmcnt(0)" ::: "memory");
        __builtin_amdgcn_s_barrier();
        asm volatile("" ::: "memory");
        buf ^= 1;
    }
    float bvv[4];
    #pragma unroll
    for (int ni = 0; ni < 4; ++ni) bvv[ni] = bias[n0 + wn*64 + ni*16 + lq];
    #pragma unroll
    for (int mi = 0; mi < 4; ++mi)
        #pragma unroll
        for (int ni = 0; ni < 4; ++ni)
            #pragma unroll
            for (int i = 0; i < 4; ++i) acc[mi][ni][i] += bvv[ni];
    int h = (n0 >> 6) + wn;
    if (mat <= 1) {
        unsigned short* outp = (mat == 0) ? qb : kb;
        float oscale = (mat == 0) ? LOG2E : 1.0f;
        #pragma unroll
        for (int mi = 0; mi < 4; ++mi) {
            f32x4 ss = 0.0f;
            #pragma unroll
            for (int ni = 0; ni < 4; ++ni)
                #pragma unroll
                for (int i = 0; i < 4; ++i) ss[i] += acc[mi][ni][i]*acc[mi][ni][i];
            #pragma unroll
            for (int off = 1; off < 16; off <<= 1)
                #pragma unroll
                for (int i = 0; i < 4; ++i) ss[i] += __shfl_xor(ss[i], off);
            #pragma unroll
            for (int i = 0; i < 4; ++i) {
                float sc = oscale / fmaxf(sqrtf(ss[i]), 1e-12f);
                int m = m0 + wm*64 + mi*16 + g*4 + i;
                int bb = m >> 11, sq = m & (SEQLEN-1);
                unsigned short* orow = outp
                    + ((size_t)(bb*NHEADS + h)*SEQLEN + sq)*HEADD;
                #pragma unroll
                for (int ni = 0; ni < 4; ++ni)
                    orow[ni*16 + lq] = f2bf(acc[mi][ni][i] * sc);
            }
        }
    } else {
        #pragma unroll
        for (int mi = 0; mi < 4; ++mi) {
            int m = m0 + wm*64 + mi*16 + g*4;
            int bb = m >> 11, sq = m & (SEQLEN-1);
            #pragma unroll
            for (int ni = 0; ni < 4; ++ni) {
                int d = ni*16 + lq;
                us4v pk;
                #pragma unroll
                for (int i = 0; i < 4; ++i) pk[i] = f2bf(acc[mi][ni][i]);
                *(us4v*)(vt + ((size_t)(bb*NHEADS + h)*HEADD + d)*SEQLEN + sq) = pk;
            }
        }
    }
}

// --------- O-projection GEMM 128x64 tile: out = A@Wt^T + bias + residual ---------
__global__ __launch_bounds__(256) void gemm_o_kernel(
        const unsigned short* __restrict__ A,
        const unsigned short* __restrict__ Wt,
        const float* __restrict__ bias,
        const float* __restrict__ residual,
        float* __restrict__ out) {
    __shared__ unsigned short As[2][128*64];
    __shared__ unsigned short Bs[2][64*64];
    int m0 = blockIdx.x * 128;
    int n0 = blockIdx.y * 64;
    int t = threadIdx.x;
    int wid = t >> 6, l = t & 63;
    int wm = wid >> 1, wn = wid & 1;
    int lq = l & 15, g = l >> 4;
    f32x4 acc[4][2];
    #pragma unroll
    for (int mi = 0; mi < 4; ++mi)
        #pragma unroll
        for (int ni = 0; ni < 2; ++ni) acc[mi][ni] = 0.0f;

    auto STAGE = [&](int b, int k0) {
        #pragma unroll
        for (int i = 0; i < 4; ++i) {
            int idx = t + 256*i;
            int r = idx >> 3, ch = idx & 7;
            int gch = ch ^ (r & 7);
            __builtin_amdgcn_global_load_lds(
                (const GLOBAL_AS void*)(A + (size_t)(m0+r)*HDIM + k0 + gch*8),
                (LDS_AS void*)((char*)&As[b][0] + idx*16), 16, 0, 0);
        }
        #pragma unroll
        for (int i = 0; i < 2; ++i) {
            int idx = t + 256*i;
            int r = idx >> 3, ch = idx & 7;
            int gch = ch ^ (r & 7);
            __builtin_amdgcn_global_load_lds(
                (const GLOBAL_AS void*)(Wt + (size_t)(n0+r)*HDIM + k0 + gch*8),
                (LDS_AS void*)((char*)&Bs[b][0] + idx*16), 16, 0, 0);
        }
    };

    STAGE(0, 0);
    asm volatile("s_waitcnt vmcnt(0)" ::: "memory");
    __builtin_amdgcn_s_barrier();
    asm volatile("" ::: "memory");
    int buf = 0;
    for (int ks = 0; ks < 16; ++ks) {
        if (ks < 15) STAGE(buf^1, (ks+1)*64);
        const char* Ab = (const char*)&As[buf][0];
        const char* Bb = (const char*)&Bs[buf][0];
        #pragma unroll
        for (int kc = 0; kc < 2; ++kc) {
            short8 af[4], bf[2];
            #pragma unroll
            for (int mi = 0; mi < 4; ++mi) {
                int r = wm*64 + mi*16 + lq;
                af[mi] = *(const short8*)(Ab + r*128 + (((kc*4+g) ^ (r&7))<<4));
            }
            #pragma unroll
            for (int ni = 0; ni < 2; ++ni) {
                int r = wn*32 + ni*16 + lq;
                bf[ni] = *(const short8*)(Bb + r*128 + (((kc*4+g) ^ (r&7))<<4));
            }
            #pragma unroll
            for (int mi = 0; mi < 4; ++mi)
                #pragma unroll
                for (int ni = 0; ni < 2; ++ni)
                    acc[mi][ni] = __builtin_amdgcn_mfma_f32_16x16x32_bf16(
                        af[mi], bf[ni], acc[mi][ni], 0, 0, 0);
        }
        asm volatile("s_waitcnt vmcnt(0)" ::: "memory");
        __builtin_amdgcn_s_barrier();
        asm volatile("" ::: "memory");
        buf ^= 1;
    }
    float bvv[2];
    #pragma unroll
    for (int ni = 0; ni < 2; ++ni) bvv[ni] = bias[n0 + wn*32 + ni*16 + lq];
    #pragma unroll
    for (int mi = 0; mi < 4; ++mi)
        #pragma unroll
        for (int i = 0; i < 4; ++i) {
            int m = m0 + wm*64 + mi*16 + g*4 + i;
            float* orow = out + (size_t)m*HDIM;
            const float* rrow = residual + (size_t)m*HDIM;
            #pragma unroll
            for (int ni = 0; ni < 2; ++ni) {
                int n = n0 + wn*32 + ni*16 + lq;
                orow[n] = acc[mi][ni][i] + bvv[ni] + rrow[n];
            }
        }
}

// ---------------- fused 2-step Hopfield attention, paired phases ----------------
// 512 threads = 4 wq x 2 ks waves; wave owns 32 q-rows x one 32-key half.
// 4x16KB staging buffers; phase p computes tiles 2p,2p+1 and stages 2p+2,2p+3.
// Combine area overlays bufs 0/1 at pass boundaries (restaged after).
__global__ __launch_bounds__(512, 4) void attn_fused_kernel(
        const unsigned short* __restrict__ qg, const unsigned short* __restrict__ kg,
        const unsigned short* __restrict__ vtg, unsigned short* __restrict__ outp) {
    __shared__ char L[4*16384];   // 64 KiB
    int b = blockIdx.x;
    int bh = (b & 7)*4 + ((b >> 3) & 3);   // 4 heads per XCD
    int q0 = (b >> 5) * 128;
    int t = threadIdx.x;
    int wid = t >> 6, l = t & 63;
    int wq = wid >> 1, ks = wid & 1;
    int q = l & 31, hi = l >> 5, r7 = q & 7;
    short8 qf[4];
    {
        const unsigned short* qrow = qg + ((size_t)bh*SEQLEN + q0 + wq*32 + q)*HEADD;
        #pragma unroll
        for (int dc = 0; dc < 4; ++dc) qf[dc] = *(const short8*)(qrow + dc*16 + hi*8);
    }
    int koffv[4];
    #pragma unroll
    for (int x = 0; x < 4; ++x) koffv[x] = q*128 + (((x*2 + hi) ^ r7) << 4);
    int vofA = koffv[2*ks], vofB = koffv[2*ks+1];   // scalarized (no runtime array idx)
    short8 ones;
    #pragma unroll
    for (int j = 0; j < 8; ++j) ones[j] = (short)0x3F80;

    f32x16 o0 = 0.0f, o1 = 0.0f, oL = 0.0f;
    const unsigned short* Kg = kg + (size_t)bh*SEQLEN*HEADD;
    const unsigned short* Vg = vtg + (size_t)bh*HEADD*SEQLEN;
    unsigned int* slot = (unsigned int*)(L + wq*4096);           // in buf0
    float* slsum = (float*)(L + 16384 + wq*256);                 // in buf1

    // hoisted staging addresses: base + tile*const stride
    int sr = t >> 3, sch = t & 7;
    int sgch = sch ^ (sr & 7);
    const unsigned short* Ksrc = Kg + sr*HEADD + sgch*8;   // += kt*4096 elems
    const unsigned short* Vsrc = Vg + (size_t)sr*SEQLEN + sgch*8; // += kt*64 elems
    auto STAGE = [&](int buf, int kt) {
        __builtin_amdgcn_global_load_lds(
            (const GLOBAL_AS void*)(Ksrc + (size_t)kt*4096),
            (LDS_AS void*)(L + buf*16384 + t*16), 16, 0, 0);
        __builtin_amdgcn_global_load_lds(
            (const GLOBAL_AS void*)(Vsrc + kt*64),
            (LDS_AS void*)(L + buf*16384 + 8192 + t*16), 16, 0, 0);
    };

    auto doTile = [&](const char* KL, const char* VL) {
        short8 kf0 = *(const short8*)(KL + koffv[0]);
        short8 kf1 = *(const short8*)(KL + koffv[1]);
        short8 kf2 = *(const short8*)(KL + koffv[2]);
        short8 kf3 = *(const short8*)(KL + koffv[3]);
        short8 va0 = *(const short8*)(VL + vofA);
        short8 va1 = *(const short8*)(VL + vofA + 4096);
        short8 vb0 = *(const short8*)(VL + vofB);
        short8 vb1 = *(const short8*)(VL + vofB + 4096);
        f32x16 s = 0.0f;
        __builtin_amdgcn_s_setprio(1);
        s = __builtin_amdgcn_mfma_f32_32x32x16_bf16(kf0, qf[0], s, 0, 0, 0);
        s = __builtin_amdgcn_mfma_f32_32x32x16_bf16(kf1, qf[1], s, 0, 0, 0);
        s = __builtin_amdgcn_mfma_f32_32x32x16_bf16(kf2, qf[2], s, 0, 0, 0);
        s = __builtin_amdgcn_mfma_f32_32x32x16_bf16(kf3, qf[3], s, 0, 0, 0);
        __builtin_amdgcn_s_setprio(0);
        unsigned int w[8];
        #pragma unroll
        for (int i = 0; i < 8; ++i) {
            float e0 = __builtin_amdgcn_exp2f(s[2*i]);
            float e1 = __builtin_amdgcn_exp2f(s[2*i+1]);
            asm("v_cvt_pk_bf16_f32 %0, %1, %2" : "=v"(w[i]) : "v"(e0), "v"(e1));
        }
        asm volatile("v_permlane32_swap_b32 %0, %1" : "+v"(w[0]), "+v"(w[2]));
        asm volatile("v_permlane32_swap_b32 %0, %1" : "+v"(w[1]), "+v"(w[3]));
        asm volatile("v_permlane32_swap_b32 %0, %1" : "+v"(w[4]), "+v"(w[6]));
        asm volatile("v_permlane32_swap_b32 %0, %1" : "+v"(w[5]), "+v"(w[7]));
        PW pa, pb;
        pa.u[0]=w[0]; pa.u[1]=w[1]; pa.u[2]=w[2]; pa.u[3]=w[3];
        pb.u[0]=w[4]; pb.u[1]=w[5]; pb.u[2]=w[6]; pb.u[3]=w[7];
        __builtin_amdgcn_s_setprio(1);
        o0 = __builtin_amdgcn_mfma_f32_32x32x16_bf16(va0, pa.s, o0, 0, 0, 0);
        o1 = __builtin_amdgcn_mfma_f32_32x32x16_bf16(va1, pa.s, o1, 0, 0, 0);
        oL = __builtin_amdgcn_mfma_f32_32x32x16_bf16(ones, pa.s, oL, 0, 0, 0);
        o0 = __builtin_amdgcn_mfma_f32_32x32x16_bf16(vb0, pb.s, o0, 0, 0, 0);
        o1 = __builtin_amdgcn_mfma_f32_32x32x16_bf16(vb1, pb.s, o1, 0, 0, 0);
        oL = __builtin_amdgcn_mfma_f32_32x32x16_bf16(ones, pb.s, oL, 0, 0, 0);
        __builtin_amdgcn_s_setprio(0);
    };

    auto runPass = [&]() {
        for (int p = 0; p < NT/2; ++p) {
            int ba = (p & 1) * 2;
            if (p < NT/2 - 1) { STAGE(ba^2, 2*p+2); STAGE((ba^2)+1, 2*p+3); }
            doTile(L + ba*16384 + ks*4096, L + ba*16384 + 8192);
            doTile(L + (ba+1)*16384 + ks*4096, L + (ba+1)*16384 + 8192);
            asm volatile("s_waitcnt vmcnt(0)" ::: "memory");
            __builtin_amdgcn_s_barrier();
            asm volatile("" ::: "memory");
        }
    };

    // ---- pass 1 ----
    STAGE(0, 0); STAGE(1, 1);
    asm volatile("s_waitcnt vmcnt(0)" ::: "memory");
    __builtin_amdgcn_s_barrier();
    asm volatile("" ::: "memory");
    runPass();
    // ---- pass boundary: combine ks halves, compute state1, share qf ----
    if (ks == 1) {
        #pragma unroll
        for (int i = 0; i < 8; ++i) {
            unsigned int u;
            asm("v_cvt_pk_bf16_f32 %0, %1, %2" : "=v"(u) : "v"(o0[2*i]), "v"(o0[2*i+1]));
            slot[i*64 + l] = u;
            asm("v_cvt_pk_bf16_f32 %0, %1, %2" : "=v"(u) : "v"(o1[2*i]), "v"(o1[2*i+1]));
            slot[(8+i)*64 + l] = u;
        }
        slsum[l] = oL[0];
        asm volatile("s_waitcnt lgkmcnt(0)" ::: "memory");
    }
    __builtin_amdgcn_s_barrier();
    asm volatile("" ::: "memory");
    if (ks == 0) {
        #pragma unroll
        for (int i = 0; i < 8; ++i) {
            unsigned int u = slot[i*64 + l];
            o0[2*i]   += __uint_as_float(u << 16);
            o0[2*i+1] += __uint_as_float(u & 0xffff0000u);
            u = slot[(8+i)*64 + l];
            o1[2*i]   += __uint_as_float(u << 16);
            o1[2*i+1] += __uint_as_float(u & 0xffff0000u);
        }
        float osc = LOG2E / (oL[0] + slsum[l]);
        unsigned int w0[8], w1[8];
        #pragma unroll
        for (int i = 0; i < 8; ++i) {
            float a0 = o0[2*i]*osc, a1 = o0[2*i+1]*osc;
            asm("v_cvt_pk_bf16_f32 %0, %1, %2" : "=v"(w0[i]) : "v"(a0), "v"(a1));
            float b0 = o1[2*i]*osc, b1 = o1[2*i+1]*osc;
            asm("v_cvt_pk_bf16_f32 %0, %1, %2" : "=v"(w1[i]) : "v"(b0), "v"(b1));
        }
        asm volatile("v_permlane32_swap_b32 %0, %1" : "+v"(w0[0]), "+v"(w0[2]));
        asm volatile("v_permlane32_swap_b32 %0, %1" : "+v"(w0[1]), "+v"(w0[3]));
        asm volatile("v_permlane32_swap_b32 %0, %1" : "+v"(w0[4]), "+v"(w0[6]));
        asm volatile("v_permlane32_swap_b32 %0, %1" : "+v"(w0[5]), "+v"(w0[7]));
        asm volatile("v_permlane32_swap_b32 %0, %1" : "+v"(w1[0]), "+v"(w1[2]));
        asm volatile("v_permlane32_swap_b32 %0, %1" : "+v"(w1[1]), "+v"(w1[3]));
        asm volatile("v_permlane32_swap_b32 %0, %1" : "+v"(w1[4]), "+v"(w1[6]));
        asm volatile("v_permlane32_swap_b32 %0, %1" : "+v"(w1[5]), "+v"(w1[7]));
        PW pa;
        pa.u[0]=w0[0]; pa.u[1]=w0[1]; pa.u[2]=w0[2]; pa.u[3]=w0[3]; qf[0]=pa.s;
        pa.u[0]=w0[4]; pa.u[1]=w0[5]; pa.u[2]=w0[6]; pa.u[3]=w0[7]; qf[1]=pa.s;
        pa.u[0]=w1[0]; pa.u[1]=w1[1]; pa.u[2]=w1[2]; pa.u[3]=w1[3]; qf[2]=pa.s;
        pa.u[0]=w1[4]; pa.u[1]=w1[5]; pa.u[2]=w1[6]; pa.u[3]=w1[7]; qf[3]=pa.s;
        #pragma unroll
        for (int i = 0; i < 8; ++i) {
            slot[i*64 + l] = w0[i];
            slot[(8+i)*64 + l] = w1[i];
        }
        asm volatile("s_waitcnt lgkmcnt(0)" ::: "memory");
    }
    __builtin_amdgcn_s_barrier();
    asm volatile("" ::: "memory");
    if (ks == 1) {
        PW pa;
        pa.u[0]=slot[0*64+l]; pa.u[1]=slot[1*64+l]; pa.u[2]=slot[2*64+l]; pa.u[3]=slot[3*64+l]; qf[0]=pa.s;
        pa.u[0]=slot[4*64+l]; pa.u[1]=slot[5*64+l]; pa.u[2]=slot[6*64+l]; pa.u[3]=slot[7*64+l]; qf[1]=pa.s;
        pa.u[0]=slot[8*64+l]; pa.u[1]=slot[9*64+l]; pa.u[2]=slot[10*64+l]; pa.u[3]=slot[11*64+l]; qf[2]=pa.s;
        pa.u[0]=slot[12*64+l]; pa.u[1]=slot[13*64+l]; pa.u[2]=slot[14*64+l]; pa.u[3]=slot[15*64+l]; qf[3]=pa.s;
    }
    asm volatile("s_waitcnt lgkmcnt(0)" ::: "memory");
    __builtin_amdgcn_s_barrier();
    asm volatile("" ::: "memory");
    o0 = 0.0f; o1 = 0.0f; oL = 0.0f;
    // ---- pass 2 ----
    STAGE(0, 0); STAGE(1, 1);
    asm volatile("s_waitcnt vmcnt(0)" ::: "memory");
    __builtin_amdgcn_s_barrier();
    asm volatile("" ::: "memory");
    runPass();
    // ---- final combine + output ----
    if (ks == 1) {
        #pragma unroll
        for (int i = 0; i < 8; ++i) {
            unsigned int u;
            asm("v_cvt_pk_bf16_f32 %0, %1, %2" : "=v"(u) : "v"(o0[2*i]), "v"(o0[2*i+1]));
            slot[i*64 + l] = u;
            asm("v_cvt_pk_bf16_f32 %0, %1, %2" : "=v"(u) : "v"(o1[2*i]), "v"(o1[2*i+1]));
            slot[(8+i)*64 + l] = u;
        }
        slsum[l] = oL[0];
        asm volatile("s_waitcnt lgkmcnt(0)" ::: "memory");
    }
    __builtin_amdgcn_s_barrier();
    asm volatile("" ::: "memory");
    if (ks == 0) {
        #pragma unroll
        for (int i = 0; i < 8; ++i) {
            unsigned int u = slot[i*64 + l];
            o0[2*i]   += __uint_as_float(u << 16);
            o0[2*i+1] += __uint_as_float(u & 0xffff0000u);
            u = slot[(8+i)*64 + l];
            o1[2*i]   += __uint_as_float(u << 16);
            o1[2*i+1] += __uint_as_float(u & 0xffff0000u);
        }
        float osc = 1.0f / (oL[0] + slsum[l]);
        int bb = bh >> 4, hh = bh & 15;
        unsigned short* orow = outp + ((size_t)bb*SEQLEN + q0 + wq*32 + q)*HDIM + hh*HEADD;
        const int dtab[8] = {0,2,8,10,16,18,24,26};
        #pragma unroll
        for (int i = 0; i < 8; ++i) {
            int d = dtab[i] + 4*hi;
            unsigned int wv;
            float a0 = o0[2*i]*osc, a1 = o0[2*i+1]*osc;
            asm("v_cvt_pk_bf16_f32 %0, %1, %2" : "=v"(wv) : "v"(a0), "v"(a1));
            *(unsigned int*)(orow + d) = wv;
            float c0 = o1[2*i]*osc, c1 = o1[2*i+1]*osc;
            asm("v_cvt_pk_bf16_f32 %0, %1, %2" : "=v"(wv) : "v"(c0), "v"(c1));
            *(unsigned int*)(orow + 32 + d) = wv;
        }
    }
}

extern "C" void kernel_launch(void* const* d_in, const int* in_sizes, int n_in,
                              void* d_out, int out_size, void* d_ws, size_t ws_size,
                              hipStream_t stream) {
    const float* hs = (const float*)d_in[0];
    const float* Wq = (const float*)d_in[1];
    const float* bq = (const float*)d_in[2];
    const float* Wk = (const float*)d_in[3];
    const float* bk = (const float*)d_in[4];
    const float* Wv = (const float*)d_in[5];
    const float* bv = (const float*)d_in[6];
    const float* Wo = (const float*)d_in[7];
    const float* bo = (const float*)d_in[8];
    const float* lw = (const float*)d_in[9];
    const float* lb = (const float*)d_in[10];
    unsigned short* ws16 = (unsigned short*)d_ws;
    const size_t NE = (size_t)NROWS * HDIM;
    const size_t WE = (size_t)HDIM * HDIM;
    unsigned short* xn  = ws16;
    unsigned short* Wtq = xn + NE;       // Wtq/Wtk/Wtv/Wto contiguous
    unsigned short* Wto = Wtq + 3*WE;
    unsigned short* qb  = Wtq + 4*WE;
    unsigned short* kb  = qb + NE;
    unsigned short* vt  = kb + NE;
    unsigned short* s2  = vt + NE;

    ln_kernel<<<NROWS, 256, 0, stream>>>(hs, lw, lb, xn);
    wconv_kernel<<<dim3(HDIM/64, HDIM/64, 4), 256, 0, stream>>>(Wq, Wk, Wv, Wo, Wtq);
    gemm_qkv_kernel<<<dim3(NROWS/128, 24), 256, 0, stream>>>(xn, Wtq, bq, bk, bv, qb, kb, vt);
    attn_fused_kernel<<<NBH*16, 512, 0, stream>>>(qb, kb, vt, s2);
    gemm_o_kernel<<<dim3(NROWS/128, HDIM/64), 256, 0, stream>>>(s2, Wto, bo, hs, (float*)d_out);
}

// Round 10
// 168.745 us; speedup vs baseline: 1.5432x; 1.1019x over previous
//
#include <hip/hip_runtime.h>
#include <hip/hip_bf16.h>
#include <math.h>

#define HDIM 1024
#define NHEADS 16
#define HEADD 64
#define SEQLEN 2048
#define NBATCH 2
#define NROWS (NBATCH*SEQLEN)
#define NBH (NBATCH*NHEADS)
#define LOG2E 1.44269504f
#define NT 32   // 64-key tiles per pass

typedef float f32x4 __attribute__((ext_vector_type(4)));
typedef float f32x16 __attribute__((ext_vector_type(16)));
typedef short short8 __attribute__((ext_vector_type(8)));
typedef unsigned short us4v __attribute__((ext_vector_type(4)));

#define GLOBAL_AS __attribute__((address_space(1)))
#define LDS_AS __attribute__((address_space(3)))

union F4 { float4 v; float f[4]; };
union PW { unsigned int u[4]; short8 s; };

static __device__ __forceinline__ unsigned short f2bf(float x) {
    __hip_bfloat16 h = __float2bfloat16(x);
    return *(unsigned short*)&h;
}

// ---------------- LayerNorm -> bf16 ----------------
__global__ __launch_bounds__(256) void ln_kernel(
        const float* __restrict__ x, const float* __restrict__ w,
        const float* __restrict__ b, unsigned short* __restrict__ xn) {
    int row = blockIdx.x;
    F4 vv; vv.v = ((const float4*)(x + (size_t)row*HDIM))[threadIdx.x];
    float s  = vv.f[0]+vv.f[1]+vv.f[2]+vv.f[3];
    float ss = vv.f[0]*vv.f[0]+vv.f[1]*vv.f[1]+vv.f[2]*vv.f[2]+vv.f[3]*vv.f[3];
    #pragma unroll
    for (int off = 32; off > 0; off >>= 1) {
        s  += __shfl_xor(s, off);
        ss += __shfl_xor(ss, off);
    }
    __shared__ float red[8];
    int wid = threadIdx.x >> 6;
    if ((threadIdx.x & 63) == 0) { red[wid] = s; red[wid+4] = ss; }
    __syncthreads();
    s  = red[0]+red[1]+red[2]+red[3];
    ss = red[4]+red[5]+red[6]+red[7];
    float mean = s * (1.0f/HDIM);
    float var  = ss * (1.0f/HDIM) - mean*mean;
    float rstd = rsqrtf(var + 1e-5f);
    F4 wv; wv.v = ((const float4*)w)[threadIdx.x];
    F4 bv; bv.v = ((const float4*)b)[threadIdx.x];
    us4v o;
    #pragma unroll
    for (int j = 0; j < 4; ++j)
        o[j] = f2bf((vv.f[j]-mean)*rstd*wv.f[j] + bv.f[j]);
    *(us4v*)(xn + (size_t)row*HDIM + threadIdx.x*4) = o;
}

// ---------- weight convert+transpose (all 4 in one launch, z=matrix) ----------
__global__ __launch_bounds__(256) void wconv_kernel(
        const float* __restrict__ W0, const float* __restrict__ W1,
        const float* __restrict__ W2, const float* __restrict__ W3,
        unsigned short* __restrict__ WtBase) {
    __shared__ unsigned short T[64*72];
    int z = blockIdx.z;
    const float* W = (z == 0) ? W0 : (z == 1) ? W1 : (z == 2) ? W2 : W3;
    unsigned short* Wt = WtBase + (size_t)z*HDIM*HDIM;
    int k0 = blockIdx.x*64, n0 = blockIdx.y*64;
    int t = threadIdx.x;
    #pragma unroll
    for (int it = 0; it < 4; ++it) {
        int r = (t>>4) + it*16;
        int c = (t&15)*4;
        F4 x; x.v = *(const float4*)(W + (size_t)(k0+r)*HDIM + n0 + c);
        #pragma unroll
        for (int j = 0; j < 4; ++j) T[(c+j)*72 + r] = f2bf(x.f[j]);
    }
    __syncthreads();
    #pragma unroll
    for (int it = 0; it < 2; ++it) {
        int n = (t>>3) + it*32;
        int ch = t&7;
        short8 rowv = *(const short8*)(T + n*72 + ch*8);
        *(short8*)(Wt + (size_t)(n0+n)*HDIM + k0 + ch*8) = rowv;
    }
}

// ------------- fused QKV GEMM: mat = blockIdx.y>>3 (0:Q 1:K 2:V) -------------
__global__ __launch_bounds__(256) void gemm_qkv_kernel(
        const unsigned short* __restrict__ A,
        const unsigned short* __restrict__ WtBase,
        const float* __restrict__ bq, const float* __restrict__ bk,
        const float* __restrict__ bv,
        unsigned short* __restrict__ qb, unsigned short* __restrict__ kb,
        unsigned short* __restrict__ vt) {
    __shared__ unsigned short As[2][128*64];
    __shared__ unsigned short Bs[2][128*64];
    int m0 = blockIdx.x * 128;
    int yy = blockIdx.y;
    int mat = yy >> 3;
    int n0 = (yy & 7) * 128;
    const unsigned short* Wt = WtBase + (size_t)mat*HDIM*HDIM;
    const float* bias = (mat == 0) ? bq : (mat == 1) ? bk : bv;
    int t = threadIdx.x;
    int wid = t >> 6, l = t & 63;
    int wm = wid >> 1, wn = wid & 1;
    int lq = l & 15, g = l >> 4;
    f32x4 acc[4][4];
    #pragma unroll
    for (int mi = 0; mi < 4; ++mi)
        #pragma unroll
        for (int ni = 0; ni < 4; ++ni) acc[mi][ni] = 0.0f;

    auto STAGE = [&](int b, int k0) {
        #pragma unroll
        for (int i = 0; i < 4; ++i) {
            int idx = t + 256*i;
            int r = idx >> 3, ch = idx & 7;
            int gch = ch ^ (r & 7);
            __builtin_amdgcn_global_load_lds(
                (const GLOBAL_AS void*)(A + (size_t)(m0+r)*HDIM + k0 + gch*8),
                (LDS_AS void*)((char*)&As[b][0] + idx*16), 16, 0, 0);
            __builtin_amdgcn_global_load_lds(
                (const GLOBAL_AS void*)(Wt + (size_t)(n0+r)*HDIM + k0 + gch*8),
                (LDS_AS void*)((char*)&Bs[b][0] + idx*16), 16, 0, 0);
        }
    };

    STAGE(0, 0);
    asm volatile("s_waitcnt vmcnt(0)" ::: "memory");
    __builtin_amdgcn_s_barrier();
    asm volatile("" ::: "memory");
    int buf = 0;
    for (int ks = 0; ks < 16; ++ks) {
        if (ks < 15) STAGE(buf^1, (ks+1)*64);
        const char* Ab = (const char*)&As[buf][0];
        const char* Bb = (const char*)&Bs[buf][0];
        #pragma unroll
        for (int kc = 0; kc < 2; ++kc) {
            short8 af[4], bf[4];
            #pragma unroll
            for (int mi = 0; mi < 4; ++mi) {
                int r = wm*64 + mi*16 + lq;
                af[mi] = *(const short8*)(Ab + r*128 + (((kc*4+g) ^ (r&7))<<4));
            }
            #pragma unroll
            for (int ni = 0; ni < 4; ++ni) {
                int r = wn*64 + ni*16 + lq;
                bf[ni] = *(const short8*)(Bb + r*128 + (((kc*4+g) ^ (r&7))<<4));
            }
            #pragma unroll
            for (int mi = 0; mi < 4; ++mi)
                #pragma unroll
                for (int ni = 0; ni < 4; ++ni)
                    acc[mi][ni] = __builtin_amdgcn_mfma_f32_16x16x32_bf16(
                        af[mi], bf[ni], acc[mi][ni], 0, 0, 0);
        }
        asm volatile("s_waitcnt vmcnt(0)" ::: "memory");
        __builtin_amdgcn_s_barrier();
        asm volatile("" ::: "memory");
        buf ^= 1;
    }
    float bvv[4];
    #pragma unroll
    for (int ni = 0; ni < 4; ++ni) bvv[ni] = bias[n0 + wn*64 + ni*16 + lq];
    #pragma unroll
    for (int mi = 0; mi < 4; ++mi)
        #pragma unroll
        for (int ni = 0; ni < 4; ++ni)
            #pragma unroll
            for (int i = 0; i < 4; ++i) acc[mi][ni][i] += bvv[ni];
    int h = (n0 >> 6) + wn;
    if (mat <= 1) {
        unsigned short* outp = (mat == 0) ? qb : kb;
        float oscale = (mat == 0) ? LOG2E : 1.0f;
        #pragma unroll
        for (int mi = 0; mi < 4; ++mi) {
            f32x4 ss = 0.0f;
            #pragma unroll
            for (int ni = 0; ni < 4; ++ni)
                #pragma unroll
                for (int i = 0; i < 4; ++i) ss[i] += acc[mi][ni][i]*acc[mi][ni][i];
            #pragma unroll
            for (int off = 1; off < 16; off <<= 1)
                #pragma unroll
                for (int i = 0; i < 4; ++i) ss[i] += __shfl_xor(ss[i], off);
            #pragma unroll
            for (int i = 0; i < 4; ++i) {
                float sc = oscale / fmaxf(sqrtf(ss[i]), 1e-12f);
                int m = m0 + wm*64 + mi*16 + g*4 + i;
                int bb = m >> 11, sq = m & (SEQLEN-1);
                unsigned short* orow = outp
                    + ((size_t)(bb*NHEADS + h)*SEQLEN + sq)*HEADD;
                #pragma unroll
                for (int ni = 0; ni < 4; ++ni)
                    orow[ni*16 + lq] = f2bf(acc[mi][ni][i] * sc);
            }
        }
    } else {
        #pragma unroll
        for (int mi = 0; mi < 4; ++mi) {
            int m = m0 + wm*64 + mi*16 + g*4;
            int bb = m >> 11, sq = m & (SEQLEN-1);
            #pragma unroll
            for (int ni = 0; ni < 4; ++ni) {
                int d = ni*16 + lq;
                us4v pk;
                #pragma unroll
                for (int i = 0; i < 4; ++i) pk[i] = f2bf(acc[mi][ni][i]);
                *(us4v*)(vt + ((size_t)(bb*NHEADS + h)*HEADD + d)*SEQLEN + sq) = pk;
            }
        }
    }
}

// --------- O-projection GEMM 128x64 tile: out = A@Wt^T + bias + residual ---------
__global__ __launch_bounds__(256) void gemm_o_kernel(
        const unsigned short* __restrict__ A,
        const unsigned short* __restrict__ Wt,
        const float* __restrict__ bias,
        const float* __restrict__ residual,
        float* __restrict__ out) {
    __shared__ unsigned short As[2][128*64];
    __shared__ unsigned short Bs[2][64*64];
    int m0 = blockIdx.x * 128;
    int n0 = blockIdx.y * 64;
    int t = threadIdx.x;
    int wid = t >> 6, l = t & 63;
    int wm = wid >> 1, wn = wid & 1;
    int lq = l & 15, g = l >> 4;
    f32x4 acc[4][2];
    #pragma unroll
    for (int mi = 0; mi < 4; ++mi)
        #pragma unroll
        for (int ni = 0; ni < 2; ++ni) acc[mi][ni] = 0.0f;

    auto STAGE = [&](int b, int k0) {
        #pragma unroll
        for (int i = 0; i < 4; ++i) {
            int idx = t + 256*i;
            int r = idx >> 3, ch = idx & 7;
            int gch = ch ^ (r & 7);
            __builtin_amdgcn_global_load_lds(
                (const GLOBAL_AS void*)(A + (size_t)(m0+r)*HDIM + k0 + gch*8),
                (LDS_AS void*)((char*)&As[b][0] + idx*16), 16, 0, 0);
        }
        #pragma unroll
        for (int i = 0; i < 2; ++i) {
            int idx = t + 256*i;
            int r = idx >> 3, ch = idx & 7;
            int gch = ch ^ (r & 7);
            __builtin_amdgcn_global_load_lds(
                (const GLOBAL_AS void*)(Wt + (size_t)(n0+r)*HDIM + k0 + gch*8),
                (LDS_AS void*)((char*)&Bs[b][0] + idx*16), 16, 0, 0);
        }
    };

    STAGE(0, 0);
    asm volatile("s_waitcnt vmcnt(0)" ::: "memory");
    __builtin_amdgcn_s_barrier();
    asm volatile("" ::: "memory");
    int buf = 0;
    for (int ks = 0; ks < 16; ++ks) {
        if (ks < 15) STAGE(buf^1, (ks+1)*64);
        const char* Ab = (const char*)&As[buf][0];
        const char* Bb = (const char*)&Bs[buf][0];
        #pragma unroll
        for (int kc = 0; kc < 2; ++kc) {
            short8 af[4], bf[2];
            #pragma unroll
            for (int mi = 0; mi < 4; ++mi) {
                int r = wm*64 + mi*16 + lq;
                af[mi] = *(const short8*)(Ab + r*128 + (((kc*4+g) ^ (r&7))<<4));
            }
            #pragma unroll
            for (int ni = 0; ni < 2; ++ni) {
                int r = wn*32 + ni*16 + lq;
                bf[ni] = *(const short8*)(Bb + r*128 + (((kc*4+g) ^ (r&7))<<4));
            }
            #pragma unroll
            for (int mi = 0; mi < 4; ++mi)
                #pragma unroll
                for (int ni = 0; ni < 2; ++ni)
                    acc[mi][ni] = __builtin_amdgcn_mfma_f32_16x16x32_bf16(
                        af[mi], bf[ni], acc[mi][ni], 0, 0, 0);
        }
        asm volatile("s_waitcnt vmcnt(0)" ::: "memory");
        __builtin_amdgcn_s_barrier();
        asm volatile("" ::: "memory");
        buf ^= 1;
    }
    float bvv[2];
    #pragma unroll
    for (int ni = 0; ni < 2; ++ni) bvv[ni] = bias[n0 + wn*32 + ni*16 + lq];
    #pragma unroll
    for (int mi = 0; mi < 4; ++mi)
        #pragma unroll
        for (int i = 0; i < 4; ++i) {
            int m = m0 + wm*64 + mi*16 + g*4 + i;
            float* orow = out + (size_t)m*HDIM;
            const float* rrow = residual + (size_t)m*HDIM;
            #pragma unroll
            for (int ni = 0; ni < 2; ++ni) {
                int n = n0 + wn*32 + ni*16 + lq;
                orow[n] = acc[mi][ni][i] + bvv[ni] + rrow[n];
            }
        }
}

// ---------------- fused 2-step Hopfield attention, paired phases ----------------
// 512 threads = 4 wq x 2 ks waves; wave owns 32 q-rows x one 32-key half.
// lsum via VALU adds (no ones-MFMA: saves 16 acc regs -> fits 128-VGPR cap, no spill).
__global__ __launch_bounds__(512, 4) void attn_fused_kernel(
        const unsigned short* __restrict__ qg, const unsigned short* __restrict__ kg,
        const unsigned short* __restrict__ vtg, unsigned short* __restrict__ outp) {
    __shared__ char L[4*16384];   // 64 KiB
    int b = blockIdx.x;
    int bh = (b & 7)*4 + ((b >> 3) & 3);   // 4 heads per XCD
    int q0 = (b >> 5) * 128;
    int t = threadIdx.x;
    int wid = t >> 6, l = t & 63;
    int wq = wid >> 1, ks = wid & 1;
    int q = l & 31, hi = l >> 5, r7 = q & 7;
    short8 qf[4];
    {
        const unsigned short* qrow = qg + ((size_t)bh*SEQLEN + q0 + wq*32 + q)*HEADD;
        #pragma unroll
        for (int dc = 0; dc < 4; ++dc) qf[dc] = *(const short8*)(qrow + dc*16 + hi*8);
    }
    int koffv[4];
    #pragma unroll
    for (int x = 0; x < 4; ++x) koffv[x] = q*128 + (((x*2 + hi) ^ r7) << 4);
    int vofA = koffv[2*ks], vofB = koffv[2*ks+1];

    f32x16 o0 = 0.0f, o1 = 0.0f;
    float ls = 0.0f;
    const unsigned short* Kg = kg + (size_t)bh*SEQLEN*HEADD;
    const unsigned short* Vg = vtg + (size_t)bh*HEADD*SEQLEN;
    unsigned int* slot = (unsigned int*)(L + wq*4096);           // in buf0
    float* slsum = (float*)(L + 16384 + wq*256);                 // in buf1

    int sr = t >> 3, sch = t & 7;
    int sgch = sch ^ (sr & 7);
    const unsigned short* Ksrc = Kg + sr*HEADD + sgch*8;
    const unsigned short* Vsrc = Vg + (size_t)sr*SEQLEN + sgch*8;
    auto STAGE = [&](int buf, int kt) {
        __builtin_amdgcn_global_load_lds(
            (const GLOBAL_AS void*)(Ksrc + (size_t)kt*4096),
            (LDS_AS void*)(L + buf*16384 + t*16), 16, 0, 0);
        __builtin_amdgcn_global_load_lds(
            (const GLOBAL_AS void*)(Vsrc + kt*64),
            (LDS_AS void*)(L + buf*16384 + 8192 + t*16), 16, 0, 0);
    };

    auto doTile = [&](const char* KL, const char* VL) {
        short8 kf0 = *(const short8*)(KL + koffv[0]);
        short8 kf1 = *(const short8*)(KL + koffv[1]);
        short8 kf2 = *(const short8*)(KL + koffv[2]);
        short8 kf3 = *(const short8*)(KL + koffv[3]);
        f32x16 s = 0.0f;
        __builtin_amdgcn_s_setprio(1);
        s = __builtin_amdgcn_mfma_f32_32x32x16_bf16(kf0, qf[0], s, 0, 0, 0);
        s = __builtin_amdgcn_mfma_f32_32x32x16_bf16(kf1, qf[1], s, 0, 0, 0);
        s = __builtin_amdgcn_mfma_f32_32x32x16_bf16(kf2, qf[2], s, 0, 0, 0);
        s = __builtin_amdgcn_mfma_f32_32x32x16_bf16(kf3, qf[3], s, 0, 0, 0);
        __builtin_amdgcn_s_setprio(0);
        unsigned int w[8];
        #pragma unroll
        for (int i = 0; i < 8; ++i) {
            float e0 = __builtin_amdgcn_exp2f(s[2*i]);
            float e1 = __builtin_amdgcn_exp2f(s[2*i+1]);
            ls += e0 + e1;
            asm("v_cvt_pk_bf16_f32 %0, %1, %2" : "=v"(w[i]) : "v"(e0), "v"(e1));
        }
        asm volatile("v_permlane32_swap_b32 %0, %1" : "+v"(w[0]), "+v"(w[2]));
        asm volatile("v_permlane32_swap_b32 %0, %1" : "+v"(w[1]), "+v"(w[3]));
        asm volatile("v_permlane32_swap_b32 %0, %1" : "+v"(w[4]), "+v"(w[6]));
        asm volatile("v_permlane32_swap_b32 %0, %1" : "+v"(w[5]), "+v"(w[7]));
        PW pa, pb;
        pa.u[0]=w[0]; pa.u[1]=w[1]; pa.u[2]=w[2]; pa.u[3]=w[3];
        pb.u[0]=w[4]; pb.u[1]=w[5]; pb.u[2]=w[6]; pb.u[3]=w[7];
        short8 va0 = *(const short8*)(VL + vofA);
        short8 va1 = *(const short8*)(VL + vofA + 4096);
        short8 vb0 = *(const short8*)(VL + vofB);
        short8 vb1 = *(const short8*)(VL + vofB + 4096);
        __builtin_amdgcn_s_setprio(1);
        o0 = __builtin_amdgcn_mfma_f32_32x32x16_bf16(va0, pa.s, o0, 0, 0, 0);
        o1 = __builtin_amdgcn_mfma_f32_32x32x16_bf16(va1, pa.s, o1, 0, 0, 0);
        o0 = __builtin_amdgcn_mfma_f32_32x32x16_bf16(vb0, pb.s, o0, 0, 0, 0);
        o1 = __builtin_amdgcn_mfma_f32_32x32x16_bf16(vb1, pb.s, o1, 0, 0, 0);
        __builtin_amdgcn_s_setprio(0);
    };

    auto runPass = [&]() {
        for (int p = 0; p < NT/2; ++p) {
            int ba = (p & 1) * 2;
            if (p < NT/2 - 1) { STAGE(ba^2, 2*p+2); STAGE((ba^2)+1, 2*p+3); }
            doTile(L + ba*16384 + ks*4096, L + ba*16384 + 8192);
            doTile(L + (ba+1)*16384 + ks*4096, L + (ba+1)*16384 + 8192);
            asm volatile("s_waitcnt vmcnt(0)" ::: "memory");
            __builtin_amdgcn_s_barrier();
            asm volatile("" ::: "memory");
        }
    };

    // ---- pass 1 ----
    STAGE(0, 0); STAGE(1, 1);
    asm volatile("s_waitcnt vmcnt(0)" ::: "memory");
    __builtin_amdgcn_s_barrier();
    asm volatile("" ::: "memory");
    runPass();
    ls += __shfl_xor(ls, 32);   // combine hi-halves (each lane held 16 of 32 keys)
    // ---- pass boundary: combine ks halves, compute state1, share qf ----
    if (ks == 1) {
        #pragma unroll
        for (int i = 0; i < 8; ++i) {
            unsigned int u;
            asm("v_cvt_pk_bf16_f32 %0, %1, %2" : "=v"(u) : "v"(o0[2*i]), "v"(o0[2*i+1]));
            slot[i*64 + l] = u;
            asm("v_cvt_pk_bf16_f32 %0, %1, %2" : "=v"(u) : "v"(o1[2*i]), "v"(o1[2*i+1]));
            slot[(8+i)*64 + l] = u;
        }
        slsum[l] = ls;
        asm volatile("s_waitcnt lgkmcnt(0)" ::: "memory");
    }
    __builtin_amdgcn_s_barrier();
    asm volatile("" ::: "memory");
    if (ks == 0) {
        #pragma unroll
        for (int i = 0; i < 8; ++i) {
            unsigned int u = slot[i*64 + l];
            o0[2*i]   += __uint_as_float(u << 16);
            o0[2*i+1] += __uint_as_float(u & 0xffff0000u);
            u = slot[(8+i)*64 + l];
            o1[2*i]   += __uint_as_float(u << 16);
            o1[2*i+1] += __uint_as_float(u & 0xffff0000u);
        }
        float osc = LOG2E / (ls + slsum[l]);
        unsigned int w0[8], w1[8];
        #pragma unroll
        for (int i = 0; i < 8; ++i) {
            float a0 = o0[2*i]*osc, a1 = o0[2*i+1]*osc;
            asm("v_cvt_pk_bf16_f32 %0, %1, %2" : "=v"(w0[i]) : "v"(a0), "v"(a1));
            float b0 = o1[2*i]*osc, b1 = o1[2*i+1]*osc;
            asm("v_cvt_pk_bf16_f32 %0, %1, %2" : "=v"(w1[i]) : "v"(b0), "v"(b1));
        }
        asm volatile("v_permlane32_swap_b32 %0, %1" : "+v"(w0[0]), "+v"(w0[2]));
        asm volatile("v_permlane32_swap_b32 %0, %1" : "+v"(w0[1]), "+v"(w0[3]));
        asm volatile("v_permlane32_swap_b32 %0, %1" : "+v"(w0[4]), "+v"(w0[6]));
        asm volatile("v_permlane32_swap_b32 %0, %1" : "+v"(w0[5]), "+v"(w0[7]));
        asm volatile("v_permlane32_swap_b32 %0, %1" : "+v"(w1[0]), "+v"(w1[2]));
        asm volatile("v_permlane32_swap_b32 %0, %1" : "+v"(w1[1]), "+v"(w1[3]));
        asm volatile("v_permlane32_swap_b32 %0, %1" : "+v"(w1[4]), "+v"(w1[6]));
        asm volatile("v_permlane32_swap_b32 %0, %1" : "+v"(w1[5]), "+v"(w1[7]));
        PW pa;
        pa.u[0]=w0[0]; pa.u[1]=w0[1]; pa.u[2]=w0[2]; pa.u[3]=w0[3]; qf[0]=pa.s;
        pa.u[0]=w0[4]; pa.u[1]=w0[5]; pa.u[2]=w0[6]; pa.u[3]=w0[7]; qf[1]=pa.s;
        pa.u[0]=w1[0]; pa.u[1]=w1[1]; pa.u[2]=w1[2]; pa.u[3]=w1[3]; qf[2]=pa.s;
        pa.u[0]=w1[4]; pa.u[1]=w1[5]; pa.u[2]=w1[6]; pa.u[3]=w1[7]; qf[3]=pa.s;
        #pragma unroll
        for (int i = 0; i < 8; ++i) {
            slot[i*64 + l] = w0[i];
            slot[(8+i)*64 + l] = w1[i];
        }
        asm volatile("s_waitcnt lgkmcnt(0)" ::: "memory");
    }
    __builtin_amdgcn_s_barrier();
    asm volatile("" ::: "memory");
    if (ks == 1) {
        PW pa;
        pa.u[0]=slot[0*64+l]; pa.u[1]=slot[1*64+l]; pa.u[2]=slot[2*64+l]; pa.u[3]=slot[3*64+l]; qf[0]=pa.s;
        pa.u[0]=slot[4*64+l]; pa.u[1]=slot[5*64+l]; pa.u[2]=slot[6*64+l]; pa.u[3]=slot[7*64+l]; qf[1]=pa.s;
        pa.u[0]=slot[8*64+l]; pa.u[1]=slot[9*64+l]; pa.u[2]=slot[10*64+l]; pa.u[3]=slot[11*64+l]; qf[2]=pa.s;
        pa.u[0]=slot[12*64+l]; pa.u[1]=slot[13*64+l]; pa.u[2]=slot[14*64+l]; pa.u[3]=slot[15*64+l]; qf[3]=pa.s;
    }
    asm volatile("s_waitcnt lgkmcnt(0)" ::: "memory");
    __builtin_amdgcn_s_barrier();
    asm volatile("" ::: "memory");
    o0 = 0.0f; o1 = 0.0f; ls = 0.0f;
    // ---- pass 2 ----
    STAGE(0, 0); STAGE(1, 1);
    asm volatile("s_waitcnt vmcnt(0)" ::: "memory");
    __builtin_amdgcn_s_barrier();
    asm volatile("" ::: "memory");
    runPass();
    ls += __shfl_xor(ls, 32);
    // ---- final combine + output ----
    if (ks == 1) {
        #pragma unroll
        for (int i = 0; i < 8; ++i) {
            unsigned int u;
            asm("v_cvt_pk_bf16_f32 %0, %1, %2" : "=v"(u) : "v"(o0[2*i]), "v"(o0[2*i+1]));
            slot[i*64 + l] = u;
            asm("v_cvt_pk_bf16_f32 %0, %1, %2" : "=v"(u) : "v"(o1[2*i]), "v"(o1[2*i+1]));
            slot[(8+i)*64 + l] = u;
        }
        slsum[l] = ls;
        asm volatile("s_waitcnt lgkmcnt(0)" ::: "memory");
    }
    __builtin_amdgcn_s_barrier();
    asm volatile("" ::: "memory");
    if (ks == 0) {
        #pragma unroll
        for (int i = 0; i < 8; ++i) {
            unsigned int u = slot[i*64 + l];
            o0[2*i]   += __uint_as_float(u << 16);
            o0[2*i+1] += __uint_as_float(u & 0xffff0000u);
            u = slot[(8+i)*64 + l];
            o1[2*i]   += __uint_as_float(u << 16);
            o1[2*i+1] += __uint_as_float(u & 0xffff0000u);
        }
        float osc = 1.0f / (ls + slsum[l]);
        int bb = bh >> 4, hh = bh & 15;
        unsigned short* orow = outp + ((size_t)bb*SEQLEN + q0 + wq*32 + q)*HDIM + hh*HEADD;
        const int dtab[8] = {0,2,8,10,16,18,24,26};
        #pragma unroll
        for (int i = 0; i < 8; ++i) {
            int d = dtab[i] + 4*hi;
            unsigned int wv;
            float a0 = o0[2*i]*osc, a1 = o0[2*i+1]*osc;
            asm("v_cvt_pk_bf16_f32 %0, %1, %2" : "=v"(wv) : "v"(a0), "v"(a1));
            *(unsigned int*)(orow + d) = wv;
            float c0 = o1[2*i]*osc, c1 = o1[2*i+1]*osc;
            asm("v_cvt_pk_bf16_f32 %0, %1, %2" : "=v"(wv) : "v"(c0), "v"(c1));
            *(unsigned int*)(orow + 32 + d) = wv;
        }
    }
}

extern "C" void kernel_launch(void* const* d_in, const int* in_sizes, int n_in,
                              void* d_out, int out_size, void* d_ws, size_t ws_size,
                              hipStream_t stream) {
    const float* hs = (const float*)d_in[0];
    const float* Wq = (const float*)d_in[1];
    const float* bq = (const float*)d_in[2];
    const float* Wk = (const float*)d_in[3];
    const float* bk = (const float*)d_in[4];
    const float* Wv = (const float*)d_in[5];
    const float* bv = (const float*)d_in[6];
    const float* Wo = (const float*)d_in[7];
    const float* bo = (const float*)d_in[8];
    const float* lw = (const float*)d_in[9];
    const float* lb = (const float*)d_in[10];
    unsigned short* ws16 = (unsigned short*)d_ws;
    const size_t NE = (size_t)NROWS * HDIM;
    const size_t WE = (size_t)HDIM * HDIM;
    unsigned short* xn  = ws16;
    unsigned short* Wtq = xn + NE;       // Wtq/Wtk/Wtv/Wto contiguous
    unsigned short* Wto = Wtq + 3*WE;
    unsigned short* qb  = Wtq + 4*WE;
    unsigned short* kb  = qb + NE;
    unsigned short* vt  = kb + NE;
    unsigned short* s2  = vt + NE;

    ln_kernel<<<NROWS, 256, 0, stream>>>(hs, lw, lb, xn);
    wconv_kernel<<<dim3(HDIM/64, HDIM/64, 4), 256, 0, stream>>>(Wq, Wk, Wv, Wo, Wtq);
    gemm_qkv_kernel<<<dim3(NROWS/128, 24), 256, 0, stream>>>(xn, Wtq, bq, bk, bv, qb, kb, vt);
    attn_fused_kernel<<<NBH*16, 512, 0, stream>>>(qb, kb, vt, s2);
    gemm_o_kernel<<<dim3(NROWS/128, HDIM/64), 256, 0, stream>>>(s2, Wto, bo, hs, (float*)d_out);
}